// Round 4
// baseline (365.318 us; speedup 1.0000x reference)
//
#include <hip/hip_runtime.h>
#include <hip/hip_bf16.h>
#include <math.h>

// Problem constants
#define N1R 65536   // B*N1 query rows
#define N2R 16384   // B*N2 point rows
#define NPB 4096    // N2 per batch
#define NQB 16384   // N1 per batch
#define CC  256     // COUT
#define NCELL 512   // 8x8x8 grid cells per batch
#define GRID_FAIL_R2 0.015625f   // (1/8)^2 coverage bound of the 27-cell block

typedef __attribute__((ext_vector_type(4))) float v4f;
typedef __attribute__((ext_vector_type(8))) short v8s;

static __device__ __forceinline__ short f2bs(float f) {
    union { __hip_bfloat16 h; short s; } u;
    u.h = __float2bfloat16(f);
    return u.s;
}

static __device__ __forceinline__ int cell_of(float x, float y, float z) {
    const int cx = min(7, (int)(x * 8.0f));
    const int cy = min(7, (int)(y * 8.0f));
    const int cz = min(7, (int)(z * 8.0f));
    return (cz << 6) | (cy << 3) | cx;
}

// branchless lexicographic (d, idx) top-3 insert; keeps b0<=b1<=b2 sorted
static __device__ __forceinline__ void ins3(float d, int si,
    float& b0, float& b1, float& b2, int& i0, int& i1, int& i2)
{
    const bool lt0 = (d < b0) | ((d == b0) & (si < i0));
    const bool lt1 = (d < b1) | ((d == b1) & (si < i1));
    const bool lt2 = (d < b2) | ((d == b2) & (si < i2));
    b2 = lt1 ? b1 : (lt2 ? d : b2);   i2 = lt1 ? i1 : (lt2 ? si : i2);
    b1 = lt0 ? b0 : (lt1 ? d : b1);   i1 = lt0 ? i0 : (lt1 ? si : i1);
    b0 = lt0 ? d  : b0;               i0 = lt0 ? si : i0;
}

// ---------------------------------------------------------------------------
// W transpose + bf16 convert: WT[n][k] = bf16(W[k][n]).  W: Kd x 256.
// ---------------------------------------------------------------------------
__global__ __launch_bounds__(256)
void wtrans_kernel(const float* __restrict__ W, short* __restrict__ WT, int Kd)
{
    const int i = blockIdx.x * 256 + threadIdx.x;   // over Kd*256
    const int k = i >> 8;
    const int n = i & 255;
    WT[(size_t)n * Kd + k] = f2bs(W[i]);
}

// ---------------------------------------------------------------------------
// Point augmentation + cell histogram: paug[i] = {x, y, z, (x*x+y*y)+z*z}
// (exact fp32, no FMA — bit-matches the reference's pp computation).
// ---------------------------------------------------------------------------
__global__ __launch_bounds__(256)
void paug_count_kernel(const float* __restrict__ p2, float4* __restrict__ paug,
                       int* __restrict__ counts_p)
{
#pragma clang fp contract(off)
    const int i = blockIdx.x * 256 + threadIdx.x;   // over N2R
    const float x = p2[(size_t)i * 3 + 0];
    const float y = p2[(size_t)i * 3 + 1];
    const float z = p2[(size_t)i * 3 + 2];
    float4 v;
    v.x = x; v.y = y; v.z = z;
    v.w = (x * x + y * y) + z * z;
    paug[i] = v;
    const int b = i >> 12;                // 4096 points per batch
    atomicAdd(&counts_p[b * NCELL + cell_of(x, y, z)], 1);
}

// ---------------------------------------------------------------------------
// Query cell histogram.
// ---------------------------------------------------------------------------
__global__ __launch_bounds__(256)
void qcount_kernel(const float* __restrict__ p1, int* __restrict__ counts_q)
{
    const int i = blockIdx.x * 256 + threadIdx.x;   // over N1R
    const float x = p1[(size_t)i * 3 + 0];
    const float y = p1[(size_t)i * 3 + 1];
    const float z = p1[(size_t)i * 3 + 2];
    const int b = i >> 14;                // 16384 queries per batch
    atomicAdd(&counts_q[b * NCELL + cell_of(x, y, z)], 1);
}

// ---------------------------------------------------------------------------
// Exclusive prefix over 512 cells, 4 batches x {points, queries}.
// Writes starts_p (with 513th sentinel) and initializes scatter cursors.
// ---------------------------------------------------------------------------
__global__ __launch_bounds__(512)
void prefix_kernel(const int* __restrict__ counts_p, int* __restrict__ cursors_p,
                   int* __restrict__ starts_p,
                   const int* __restrict__ counts_q, int* __restrict__ cursors_q)
{
    __shared__ int sc[512];
    const int t = threadIdx.x;
    for (int a = 0; a < 8; ++a) {
        const int b = a & 3;
        const int* cnt = (a < 4) ? counts_p + b * NCELL : counts_q + b * NCELL;
        const int v = cnt[t];
        sc[t] = v;
        __syncthreads();
        for (int off = 1; off < 512; off <<= 1) {
            const int add = (t >= off) ? sc[t - off] : 0;
            __syncthreads();
            sc[t] += add;
            __syncthreads();
        }
        const int incl = sc[t];
        const int excl = incl - v;
        if (a < 4) {
            starts_p[b * 513 + t] = excl;
            if (t == 511) starts_p[b * 513 + 512] = incl;   // == 4096
            cursors_p[b * NCELL + t] = excl;
        } else {
            cursors_q[b * NCELL + t] = excl;
        }
        __syncthreads();
    }
}

// ---------------------------------------------------------------------------
// Scatter points into cell-sorted order (batch-relative), keep original idx.
// ---------------------------------------------------------------------------
__global__ __launch_bounds__(256)
void scatter_p_kernel(const float4* __restrict__ paug, int* __restrict__ cursors,
                      float4* __restrict__ sortedP, unsigned short* __restrict__ sIdx)
{
    const int i = blockIdx.x * 256 + threadIdx.x;   // over N2R
    const float4 v = paug[i];
    const int b = i >> 12;
    const int cell = cell_of(v.x, v.y, v.z);
    const int pos = atomicAdd(&cursors[b * NCELL + cell], 1);
    sortedP[(size_t)b * NPB + pos] = v;
    sIdx[(size_t)b * NPB + pos] = (unsigned short)(i & 4095);
}

// ---------------------------------------------------------------------------
// Scatter queries into cell-sorted order (batch-local u16 ids).
// ---------------------------------------------------------------------------
__global__ __launch_bounds__(256)
void scatter_q_kernel(const float* __restrict__ p1, int* __restrict__ cursors,
                      unsigned short* __restrict__ qlist)
{
    const int i = blockIdx.x * 256 + threadIdx.x;   // over N1R
    const float x = p1[(size_t)i * 3 + 0];
    const float y = p1[(size_t)i * 3 + 1];
    const float z = p1[(size_t)i * 3 + 2];
    const int b = i >> 14;
    const int cell = cell_of(x, y, z);
    const int pos = atomicAdd(&cursors[b * NCELL + cell], 1);
    qlist[(size_t)b * NQB + pos] = (unsigned short)(i & 16383);
}

// ---------------------------------------------------------------------------
// Fused tiled GEMM + column-stats, BARRIER-FREE / LDS-FREE.
// Y = X(rows x KD, f32) @ WT^T + bias; atomicAdd per-column sum/sumsq of Y.
//
// 128x128 tile, 4 waves (2x2 quadrants of 64x64, 4x4 MFMA frags each).
// A-fragments are loaded per-lane DIRECTLY from global (32B contiguous per
// lane: row wm0+mi*16+col, k quad*8..+7) and converted f32->bf16 in-reg.
// A wave's instruction touches 16 rows x 128B contiguous segments — fully
// line-utilized; the 2-way duplication between wave pairs hits L1/L2.
// No __shared__, no __syncthreads in the K-loop: waves run free, the
// compiler pipelines the 12 loads/iter across iterations (KD is a
// compile-time constant, unroll 2).  B (WT) is 128-256KB, L2-resident.
// ---------------------------------------------------------------------------
template<int KD>
__global__ __launch_bounds__(256)
void gemm_fused_kernel(const float* __restrict__ X,
                       const short* __restrict__ WT,
                       const float* __restrict__ bias,
                       float* __restrict__ Y,
                       float* __restrict__ sum, float* __restrict__ sumsq)
{
    const int bm0 = blockIdx.x * 128;
    const int bn0 = blockIdx.y * 128;
    const int wave = threadIdx.x >> 6;
    const int lane = threadIdx.x & 63;
    const int wm0 = (wave >> 1) * 64;
    const int wn0 = (wave & 1) * 64;
    const int col = lane & 15, quad = lane >> 4;

    v4f acc[4][4];
#pragma unroll
    for (int i = 0; i < 4; ++i)
#pragma unroll
        for (int j = 0; j < 4; ++j) acc[i][j] = (v4f){0.f, 0.f, 0.f, 0.f};

    const short* wbase = WT + (size_t)(bn0 + wn0 + col) * KD + quad * 8;
    const float* xbase = X + (size_t)(bm0 + wm0 + col) * KD + quad * 8;

#pragma unroll 2
    for (int k0 = 0; k0 < KD; k0 += 32) {
        v8s bf[4];
#pragma unroll
        for (int ni = 0; ni < 4; ++ni)
            bf[ni] = *(const v8s*)(wbase + (size_t)(ni * 16) * KD + k0);

        v8s a[4];
#pragma unroll
        for (int mi = 0; mi < 4; ++mi) {
            const float* xp = xbase + (size_t)(mi * 16) * KD + k0;
            const v4f p = *(const v4f*)xp;
            const v4f q = *(const v4f*)(xp + 4);
            v8s t;
#pragma unroll
            for (int j = 0; j < 4; ++j) { t[j] = f2bs(p[j]); t[j + 4] = f2bs(q[j]); }
            a[mi] = t;
        }

#pragma unroll
        for (int mi = 0; mi < 4; ++mi)
#pragma unroll
            for (int ni = 0; ni < 4; ++ni)
                acc[mi][ni] = __builtin_amdgcn_mfma_f32_16x16x32_bf16(a[mi], bf[ni], acc[mi][ni], 0, 0, 0);
    }

    // epilogue: bias + store + fused column stats (sum / sumsq over rows)
#pragma unroll
    for (int ni = 0; ni < 4; ++ni) {
        const int n = bn0 + wn0 + ni * 16 + col;
        const float bv = bias[n];
        float s = 0.f, q = 0.f;
#pragma unroll
        for (int mi = 0; mi < 4; ++mi) {
            const int m = bm0 + wm0 + mi * 16 + quad * 4;
#pragma unroll
            for (int r = 0; r < 4; ++r) {
                const float y = acc[mi][ni][r] + bv;
                Y[(size_t)(m + r) * CC + n] = y;
                s += y; q += y * y;
            }
        }
        s += __shfl_xor(s, 16); q += __shfl_xor(q, 16);
        s += __shfl_xor(s, 32); q += __shfl_xor(q, 32);
        if (quad == 0) { atomicAdd(&sum[n], s); atomicAdd(&sumsq[n], q); }
    }
}

// ---------------------------------------------------------------------------
// Finalize BN constants: a = g*rsqrt(var+eps), c = beta - a*mu
// ---------------------------------------------------------------------------
__global__ __launch_bounds__(512)
void finalize_kernel(const float* __restrict__ sums,
                     const float* __restrict__ g1, const float* __restrict__ be1,
                     const float* __restrict__ g2, const float* __restrict__ be2,
                     float* __restrict__ ac)
{
    const int t = threadIdx.x;           // 0..511
    const int c = t & 255;
    const int which = t >> 8;            // 0: BN1, 1: BN2
    const float* s = sums + which * 512;
    const double n = which ? (double)N2R : (double)N1R;
    const double mu = (double)s[c] / n;
    const double var = (double)s[c + 256] / n - mu * mu;
    const float g  = which ? g2[c]  : g1[c];
    const float be = which ? be2[c] : be1[c];
    const double a  = (double)g / sqrt(var + 1e-5);
    const double cv = (double)be - a * mu;
    ac[which * 512 + c]       = (float)a;
    ac[which * 512 + 256 + c] = (float)cv;
}

// ---------------------------------------------------------------------------
// Grid KNN: cell-sorted queries scan their 27-cell neighborhood against the
// batch's cell-sorted points staged in LDS.  Exact fp32 distances
// (bit-matching the reference); lexicographic (d, idx) top-3.  Coverage:
// every point within 0.125 of q lies inside the clamped 27-cell block, so
// b2 < 0.125^2 certifies exactness; else brute-force fallback.
// Block: 256 thr = 128 queries x 2 half-scans (cells 0..13 / 14..26).
// ---------------------------------------------------------------------------
__global__ __launch_bounds__(256)
void knn_grid_kernel(const float* __restrict__ p1,
                     const float4* __restrict__ sortedP,
                     const unsigned short* __restrict__ sIdx16,
                     const int* __restrict__ starts_p,
                     const unsigned short* __restrict__ qlist,
                     int* __restrict__ idx_out, float* __restrict__ w_out,
                     int* __restrict__ failCount, int* __restrict__ failList)
{
#pragma clang fp contract(off)
    __shared__ float4 sP[NPB];                 // 64 KB
    __shared__ unsigned short sI[NPB];         // 8 KB
    __shared__ int sS[513];                    // 2 KB
    __shared__ float mD[128 * 3];              // 1.5 KB
    __shared__ int   mI[128 * 3];              // 1.5 KB

    const int b = blockIdx.x >> 7;             // 128 blocks per batch
    const int slot0 = (blockIdx.x & 127) * 128;
    const int tid = threadIdx.x;
    const int lq = tid & 127;                  // query slot within block
    const int half = tid >> 7;

    // stage the batch's cell-sorted points + idx + starts
    {
        const float4* gp = sortedP + (size_t)b * NPB;
        for (int i = tid; i < NPB; i += 256) sP[i] = gp[i];
        const unsigned int* gi = (const unsigned int*)(sIdx16 + (size_t)b * NPB);
        unsigned int* li = (unsigned int*)sI;
        for (int i = tid; i < NPB / 2; i += 256) li[i] = gi[i];
        const int* gs = starts_p + b * 513;
        for (int i = tid; i < 513; i += 256) sS[i] = gs[i];
    }

    const int q = qlist[(size_t)b * NQB + slot0 + lq];   // batch-local query id
    const int qid = b * NQB + q;
    const float qx = p1[(size_t)qid * 3 + 0];
    const float qy = p1[(size_t)qid * 3 + 1];
    const float qz = p1[(size_t)qid * 3 + 2];
    const float qq = (qx * qx + qy * qy) + qz * qz;
    const int cqx = min(7, (int)(qx * 8.0f));
    const int cqy = min(7, (int)(qy * 8.0f));
    const int cqz = min(7, (int)(qz * 8.0f));

    __syncthreads();

    float b0 = 3.0e38f, b1 = 3.0e38f, b2 = 3.0e38f;
    int i0 = 0x7fffffff, i1 = 0x7fffffff, i2 = 0x7fffffff;

    int n = 0;
    for (int dz = -1; dz <= 1; ++dz)
        for (int dy = -1; dy <= 1; ++dy)
            for (int dx = -1; dx <= 1; ++dx, ++n) {
                if (half ? (n < 14) : (n >= 14)) continue;   // 14 / 13 cell split
                const int cz = cqz + dz, cy = cqy + dy, cx = cqx + dx;
                if (((unsigned)cz | (unsigned)cy | (unsigned)cx) > 7u) continue;
                const int cell = (cz << 6) | (cy << 3) | cx;
                const int ks = sS[cell], ke = sS[cell + 1];
                for (int k = ks; k < ke; ++k) {
                    const float4 P = sP[k];
                    const int si = sI[k];
                    const float dot = fmaf(qz, P.z, fmaf(qy, P.y, qx * P.x));
                    const float d = fmaf(-2.0f, dot, qq + P.w);
                    ins3(d, si, b0, b1, b2, i0, i1, i2);
                }
            }

    if (half) {
        mD[lq * 3 + 0] = b0; mD[lq * 3 + 1] = b1; mD[lq * 3 + 2] = b2;
        mI[lq * 3 + 0] = i0; mI[lq * 3 + 1] = i1; mI[lq * 3 + 2] = i2;
    }
    __syncthreads();
    if (!half) {
#pragma unroll
        for (int r = 0; r < 3; ++r)
            ins3(mD[lq * 3 + r], mI[lq * 3 + r], b0, b1, b2, i0, i1, i2);

        if (!(b2 < GRID_FAIL_R2)) {            // includes <3-found case (b2=3e38)
            const int p = atomicAdd(failCount, 1);
            if (p < N1R) failList[p] = qid;    // capacity-exact; guard is free
        }
        const float r0 = 1.0f / (fmaxf(b0, 0.0f) + 1e-8f);
        const float r1 = 1.0f / (fmaxf(b1, 0.0f) + 1e-8f);
        const float r2 = 1.0f / (fmaxf(b2, 0.0f) + 1e-8f);
        const float rs = (r0 + r1) + r2;
        idx_out[(size_t)qid * 3 + 0] = i0;
        idx_out[(size_t)qid * 3 + 1] = i1;
        idx_out[(size_t)qid * 3 + 2] = i2;
        w_out[(size_t)qid * 3 + 0] = r0 / rs;
        w_out[(size_t)qid * 3 + 1] = r1 / rs;
        w_out[(size_t)qid * 3 + 2] = r2 / rs;
    }
}

// ---------------------------------------------------------------------------
// Brute-force fallback: one wave per failed query, lanes split 4096 points,
// butterfly shuffle-merge of per-lane top-3 triples.  Exact, tiny workload.
// ---------------------------------------------------------------------------
__global__ __launch_bounds__(256)
void knn_bf_kernel(const float* __restrict__ p1,
                   const float4* __restrict__ paug,
                   const int* __restrict__ failCount,
                   const int* __restrict__ failList,
                   int* __restrict__ idx_out, float* __restrict__ w_out)
{
#pragma clang fp contract(off)
    const int nf = min(*failCount, N1R);
    const int gw = (blockIdx.x * 256 + threadIdx.x) >> 6;
    const int lane = threadIdx.x & 63;
    const int nw = (gridDim.x * 256) >> 6;

    for (int fi = gw; fi < nf; fi += nw) {
        const int qid = failList[fi];
        const int b = qid >> 14;
        const float qx = p1[(size_t)qid * 3 + 0];
        const float qy = p1[(size_t)qid * 3 + 1];
        const float qz = p1[(size_t)qid * 3 + 2];
        const float qq = (qx * qx + qy * qy) + qz * qz;

        float b0 = 3.0e38f, b1 = 3.0e38f, b2 = 3.0e38f;
        int i0 = 0x7fffffff, i1 = 0x7fffffff, i2 = 0x7fffffff;

        const float4* pb = paug + (size_t)b * NPB;
        for (int j = lane; j < NPB; j += 64) {
            const float4 P = pb[j];
            const float dot = fmaf(qz, P.z, fmaf(qy, P.y, qx * P.x));
            const float d = fmaf(-2.0f, dot, qq + P.w);
            ins3(d, j, b0, b1, b2, i0, i1, i2);
        }
        // butterfly merge across the wave
        for (int m = 1; m < 64; m <<= 1) {
            const float c0 = __shfl_xor(b0, m), c1 = __shfl_xor(b1, m), c2 = __shfl_xor(b2, m);
            const int j0 = __shfl_xor(i0, m), j1 = __shfl_xor(i1, m), j2 = __shfl_xor(i2, m);
            ins3(c0, j0, b0, b1, b2, i0, i1, i2);
            ins3(c1, j1, b0, b1, b2, i0, i1, i2);
            ins3(c2, j2, b0, b1, b2, i0, i1, i2);
        }
        if (lane == 0) {
            const float r0 = 1.0f / (fmaxf(b0, 0.0f) + 1e-8f);
            const float r1 = 1.0f / (fmaxf(b1, 0.0f) + 1e-8f);
            const float r2 = 1.0f / (fmaxf(b2, 0.0f) + 1e-8f);
            const float rs = (r0 + r1) + r2;
            idx_out[(size_t)qid * 3 + 0] = i0;
            idx_out[(size_t)qid * 3 + 1] = i1;
            idx_out[(size_t)qid * 3 + 2] = i2;
            w_out[(size_t)qid * 3 + 0] = r0 / rs;
            w_out[(size_t)qid * 3 + 1] = r1 / rs;
            w_out[(size_t)qid * 3 + 2] = r2 / rs;
        }
    }
}

// ---------------------------------------------------------------------------
// Final: out[r][c] = relu(a1*Y1+c1) + sum_k w_k * relu(a2*Y2[idx_k]+c2).
// BN+ReLU of f2 fused into the gather (Y2 stays raw; bnrelu pass removed).
// ---------------------------------------------------------------------------
__global__ __launch_bounds__(256)
void final_kernel(float* __restrict__ Y1out,
                  const float* __restrict__ Y2raw,
                  const float* __restrict__ ac,        // a1,c1,a2,c2 (256 each)
                  const int* __restrict__ idx, const float* __restrict__ w)
{
    const int r = blockIdx.x * 4 + (threadIdx.x >> 6);
    const int cg = threadIdx.x & 63;
    const int b = r >> 14;

    v4f a1 = *(const v4f*)(ac + cg * 4);
    v4f c1 = *(const v4f*)(ac + 256 + cg * 4);
    v4f a2 = *(const v4f*)(ac + 512 + cg * 4);
    v4f c2 = *(const v4f*)(ac + 768 + cg * 4);
    v4f y = *(const v4f*)(Y1out + (size_t)r * CC + cg * 4);
    v4f s;
#pragma unroll
    for (int j = 0; j < 4; ++j)
        s[j] = fmaxf(fmaf(a1[j], y[j], c1[j]), 0.f);

    const int*   ir = idx + (size_t)r * 3;
    const float* wr = w   + (size_t)r * 3;
#pragma unroll
    for (int k = 0; k < 3; ++k) {
        const int id = ir[k];
        const float wk = wr[k];
        v4f g = *(const v4f*)(Y2raw + ((size_t)(b * NPB + id)) * CC + cg * 4);
#pragma unroll
        for (int j = 0; j < 4; ++j) {
            const float gv = fmaxf(fmaf(a2[j], g[j], c2[j]), 0.f);   // == bnrelu
            s[j] = fmaf(wk, gv, s[j]);
        }
    }
    *(v4f*)(Y1out + (size_t)r * CC + cg * 4) = s;
}

// ---------------------------------------------------------------------------
extern "C" void kernel_launch(void* const* d_in, const int* in_sizes, int n_in,
                              void* d_out, int out_size, void* d_ws, size_t ws_size,
                              hipStream_t stream)
{
    const float* point1 = (const float*)d_in[0];
    const float* feat1  = (const float*)d_in[1];
    const float* point2 = (const float*)d_in[2];
    const float* feat2  = (const float*)d_in[3];
    const float* W1     = (const float*)d_in[4];
    const float* b1     = (const float*)d_in[5];
    const float* g1     = (const float*)d_in[6];
    const float* beta1  = (const float*)d_in[7];
    const float* W2     = (const float*)d_in[8];
    const float* b2     = (const float*)d_in[9];
    const float* g2     = (const float*)d_in[10];
    const float* beta2  = (const float*)d_in[11];

    float* Y1 = (float*)d_out;                            // 64 MB (reused as output)

    char* ws = (char*)d_ws;
    float*          Y2       = (float*)ws;                                   // 16 MB (raw, BN fused in final)
    float*          stats    = (float*)(ws + (size_t)16777216);              // 4 KB
    int*            counts_p = (int*)  (ws + (size_t)16781312);              // 8 KB
    int*            counts_q = (int*)  (ws + (size_t)16789504);              // 8 KB
    int*            failCnt  = (int*)  (ws + (size_t)16797696);              // 4 KB pad
    int*            cursors_p= (int*)  (ws + (size_t)16801792);              // 8 KB
    int*            cursors_q= (int*)  (ws + (size_t)16809984);              // 8 KB
    int*            starts_p = (int*)  (ws + (size_t)16818176);              // 8.2 KB
    float*          ac       = (float*)(ws + (size_t)16826624);              // 4 KB
    unsigned short* sIdx16   = (unsigned short*)(ws + (size_t)16830720);     // 32 KB
    unsigned short* qlist    = (unsigned short*)(ws + (size_t)16863488);     // 128 KB
    int*            failList = (int*)  (ws + (size_t)16994560);              // 256 KB
    float4*         sortedP  = (float4*)(ws + (size_t)17256704);             // 256 KB
    int*            idxb     = (int*)  (ws + (size_t)17518848);              // 768 KB
    float*          wb       = (float*)(ws + (size_t)18305280);              // 768 KB
    short*          WT1      = (short*)(ws + (size_t)19091712);              // 128 KB
    short*          WT2      = (short*)(ws + (size_t)19222784);              // 256 KB
    float4*         paug     = (float4*)(ws + (size_t)19484928);             // 256 KB

    // zero: stats (4KB) + counts_p (8KB) + counts_q (8KB) + failCnt (4KB)
    hipMemsetAsync(stats, 0, 24576, stream);

    // Tiny prep kernels
    wtrans_kernel<<<256, 256, 0, stream>>>(W1, WT1, 256);
    wtrans_kernel<<<512, 256, 0, stream>>>(W2, WT2, 512);

    // Cell-grid build: histograms -> prefix/cursors -> scatters
    paug_count_kernel<<<N2R / 256, 256, 0, stream>>>(point2, paug, counts_p);
    qcount_kernel<<<N1R / 256, 256, 0, stream>>>(point1, counts_q);
    prefix_kernel<<<1, 512, 0, stream>>>(counts_p, cursors_p, starts_p, counts_q, cursors_q);
    scatter_p_kernel<<<N2R / 256, 256, 0, stream>>>(paug, cursors_p, sortedP, sIdx16);
    scatter_q_kernel<<<N1R / 256, 256, 0, stream>>>(point1, cursors_q, qlist);

    // Fused GEMM + BN stats (barrier-free): grid = (rows/128, 256/128)
    gemm_fused_kernel<256><<<dim3(N1R / 128, 2), 256, 0, stream>>>(feat1, WT1, b1, Y1,
                                                                   stats + 0,   stats + 256);
    gemm_fused_kernel<512><<<dim3(N2R / 128, 2), 256, 0, stream>>>(feat2, WT2, b2, Y2,
                                                                   stats + 512, stats + 768);

    finalize_kernel<<<1, 512, 0, stream>>>(stats, g1, beta1, g2, beta2, ac);

    // Grid KNN (exact) + brute-force fallback for boundary failures
    knn_grid_kernel<<<512, 256, 0, stream>>>(point1, sortedP, sIdx16, starts_p,
                                             qlist, idxb, wb, failCnt, failList);
    knn_bf_kernel<<<256, 256, 0, stream>>>(point1, paug, failCnt, failList, idxb, wb);

    // out = relu(bn(Y1)) + weighted gather of relu(bn(Y2))  (in-place on d_out)
    final_kernel<<<N1R / 4, 256, 0, stream>>>(Y1, Y2, ac, idxb, wb);
}

// Round 5
// 345.535 us; speedup vs baseline: 1.0573x; 1.0573x over previous
//
#include <hip/hip_runtime.h>
#include <hip/hip_bf16.h>
#include <math.h>

// Problem constants
#define N1R 65536   // B*N1 query rows
#define N2R 16384   // B*N2 point rows
#define NPB 4096    // N2 per batch
#define NQB 16384   // N1 per batch
#define CC  256     // COUT
#define ASTRIDE 40  // LDS A-tile row stride in bf16 elems (80B: 16B-aligned, ~2-way banks)
#define NCELL 512   // 8x8x8 grid cells per batch
#define GRID_FAIL_R2 0.015625f   // (1/8)^2 coverage bound of the 27-cell block

typedef __attribute__((ext_vector_type(4))) float v4f;
typedef __attribute__((ext_vector_type(8))) short v8s;

static __device__ __forceinline__ short f2bs(float f) {
    union { __hip_bfloat16 h; short s; } u;
    u.h = __float2bfloat16(f);
    return u.s;
}

static __device__ __forceinline__ int cell_of(float x, float y, float z) {
    const int cx = min(7, (int)(x * 8.0f));
    const int cy = min(7, (int)(y * 8.0f));
    const int cz = min(7, (int)(z * 8.0f));
    return (cz << 6) | (cy << 3) | cx;
}

// branchless lexicographic (d, idx) top-3 insert; keeps b0<=b1<=b2 sorted
static __device__ __forceinline__ void ins3(float d, int si,
    float& b0, float& b1, float& b2, int& i0, int& i1, int& i2)
{
    const bool lt0 = (d < b0) | ((d == b0) & (si < i0));
    const bool lt1 = (d < b1) | ((d == b1) & (si < i1));
    const bool lt2 = (d < b2) | ((d == b2) & (si < i2));
    b2 = lt1 ? b1 : (lt2 ? d : b2);   i2 = lt1 ? i1 : (lt2 ? si : i2);
    b1 = lt0 ? b0 : (lt1 ? d : b1);   i1 = lt0 ? i0 : (lt1 ? si : i1);
    b0 = lt0 ? d  : b0;               i0 = lt0 ? si : i0;
}

// ---------------------------------------------------------------------------
// W transpose + bf16 convert: WT[n][k] = bf16(W[k][n]).  W: Kd x 256.
// ---------------------------------------------------------------------------
__global__ __launch_bounds__(256)
void wtrans_kernel(const float* __restrict__ W, short* __restrict__ WT, int Kd)
{
    const int i = blockIdx.x * 256 + threadIdx.x;   // over Kd*256
    const int k = i >> 8;
    const int n = i & 255;
    WT[(size_t)n * Kd + k] = f2bs(W[i]);
}

// ---------------------------------------------------------------------------
// Point augmentation + cell histogram: paug[i] = {x, y, z, (x*x+y*y)+z*z}
// (exact fp32, no FMA — bit-matches the reference's pp computation).
// ---------------------------------------------------------------------------
__global__ __launch_bounds__(256)
void paug_count_kernel(const float* __restrict__ p2, float4* __restrict__ paug,
                       int* __restrict__ counts_p)
{
#pragma clang fp contract(off)
    const int i = blockIdx.x * 256 + threadIdx.x;   // over N2R
    const float x = p2[(size_t)i * 3 + 0];
    const float y = p2[(size_t)i * 3 + 1];
    const float z = p2[(size_t)i * 3 + 2];
    float4 v;
    v.x = x; v.y = y; v.z = z;
    v.w = (x * x + y * y) + z * z;
    paug[i] = v;
    const int b = i >> 12;                // 4096 points per batch
    atomicAdd(&counts_p[b * NCELL + cell_of(x, y, z)], 1);
}

// ---------------------------------------------------------------------------
// Query cell histogram.
// ---------------------------------------------------------------------------
__global__ __launch_bounds__(256)
void qcount_kernel(const float* __restrict__ p1, int* __restrict__ counts_q)
{
    const int i = blockIdx.x * 256 + threadIdx.x;   // over N1R
    const float x = p1[(size_t)i * 3 + 0];
    const float y = p1[(size_t)i * 3 + 1];
    const float z = p1[(size_t)i * 3 + 2];
    const int b = i >> 14;                // 16384 queries per batch
    atomicAdd(&counts_q[b * NCELL + cell_of(x, y, z)], 1);
}

// ---------------------------------------------------------------------------
// Exclusive prefix over 512 cells, 4 batches x {points, queries}.
// Writes starts_p (with 513th sentinel) and initializes scatter cursors.
// ---------------------------------------------------------------------------
__global__ __launch_bounds__(512)
void prefix_kernel(const int* __restrict__ counts_p, int* __restrict__ cursors_p,
                   int* __restrict__ starts_p,
                   const int* __restrict__ counts_q, int* __restrict__ cursors_q)
{
    __shared__ int sc[512];
    const int t = threadIdx.x;
    for (int a = 0; a < 8; ++a) {
        const int b = a & 3;
        const int* cnt = (a < 4) ? counts_p + b * NCELL : counts_q + b * NCELL;
        const int v = cnt[t];
        sc[t] = v;
        __syncthreads();
        for (int off = 1; off < 512; off <<= 1) {
            const int add = (t >= off) ? sc[t - off] : 0;
            __syncthreads();
            sc[t] += add;
            __syncthreads();
        }
        const int incl = sc[t];
        const int excl = incl - v;
        if (a < 4) {
            starts_p[b * 513 + t] = excl;
            if (t == 511) starts_p[b * 513 + 512] = incl;   // == 4096
            cursors_p[b * NCELL + t] = excl;
        } else {
            cursors_q[b * NCELL + t] = excl;
        }
        __syncthreads();
    }
}

// ---------------------------------------------------------------------------
// Scatter points into cell-sorted order (batch-relative), keep original idx.
// ---------------------------------------------------------------------------
__global__ __launch_bounds__(256)
void scatter_p_kernel(const float4* __restrict__ paug, int* __restrict__ cursors,
                      float4* __restrict__ sortedP, unsigned short* __restrict__ sIdx)
{
    const int i = blockIdx.x * 256 + threadIdx.x;   // over N2R
    const float4 v = paug[i];
    const int b = i >> 12;
    const int cell = cell_of(v.x, v.y, v.z);
    const int pos = atomicAdd(&cursors[b * NCELL + cell], 1);
    sortedP[(size_t)b * NPB + pos] = v;
    sIdx[(size_t)b * NPB + pos] = (unsigned short)(i & 4095);
}

// ---------------------------------------------------------------------------
// Scatter queries into cell-sorted order (batch-local u16 ids).
// ---------------------------------------------------------------------------
__global__ __launch_bounds__(256)
void scatter_q_kernel(const float* __restrict__ p1, int* __restrict__ cursors,
                      unsigned short* __restrict__ qlist)
{
    const int i = blockIdx.x * 256 + threadIdx.x;   // over N1R
    const float x = p1[(size_t)i * 3 + 0];
    const float y = p1[(size_t)i * 3 + 1];
    const float z = p1[(size_t)i * 3 + 2];
    const int b = i >> 14;
    const int cell = cell_of(x, y, z);
    const int pos = atomicAdd(&cursors[b * NCELL + cell], 1);
    qlist[(size_t)b * NQB + pos] = (unsigned short)(i & 16383);
}

// ---------------------------------------------------------------------------
// Fused tiled GEMM + column-stats: Y = X(rows x Kdim, fp32) @ WT^T + bias,
// and atomicAdd per-column sum/sumsq of Y (for BN) from the accumulators.
//
// K-loop structure is the round-2 proven one (55.5 us @ KD=256): 256 thr /
// 4 waves per 128x128 tile; wave -> 64x64 quadrant (4x4 MFMA grid).
// Reg-staged LDS (global->VGPR->cvt->ds_write), ASTRIDE=40 padding,
// software-pipelined: next A-chunk global loads issued during current MFMA.
// ---------------------------------------------------------------------------
__global__ __launch_bounds__(256)
void gemm_fused_kernel(const float* __restrict__ X,
                       const short* __restrict__ WT,
                       const float* __restrict__ bias,
                       float* __restrict__ Y,
                       float* __restrict__ sum, float* __restrict__ sumsq,
                       int Kdim)
{
    __shared__ short As[128 * ASTRIDE];

    const int bm0 = blockIdx.x * 128;
    const int bn0 = blockIdx.y * 128;
    const int wave = threadIdx.x >> 6;
    const int lane = threadIdx.x & 63;
    const int wm0 = (wave >> 1) * 64;
    const int wn0 = (wave & 1) * 64;
    const int col = lane & 15, quad = lane >> 4;

    const int srow = threadIdx.x >> 1;
    const int skh  = (threadIdx.x & 1) * 16;
    const float* sbase = X + (size_t)(bm0 + srow) * Kdim + skh;
    short* sdst = As + srow * ASTRIDE + skh;

    v4f acc[4][4];
#pragma unroll
    for (int i = 0; i < 4; ++i)
#pragma unroll
        for (int j = 0; j < 4; ++j) acc[i][j] = (v4f){0.f, 0.f, 0.f, 0.f};

    const short* wbase = WT + (size_t)(bn0 + wn0 + col) * Kdim + quad * 8;

    // prologue A prefetch
    v4f f0 = *(const v4f*)(sbase);
    v4f f1 = *(const v4f*)(sbase + 4);
    v4f f2v = *(const v4f*)(sbase + 8);
    v4f f3 = *(const v4f*)(sbase + 12);

    for (int k0 = 0; k0 < Kdim; k0 += 32) {
        v8s lo, hi;
#pragma unroll
        for (int j = 0; j < 4; ++j) {
            lo[j] = f2bs(f0[j]); lo[j + 4] = f2bs(f1[j]);
            hi[j] = f2bs(f2v[j]); hi[j + 4] = f2bs(f3[j]);
        }
        __syncthreads();   // previous iteration's LDS reads complete
        *(v8s*)sdst = lo;
        *(v8s*)(sdst + 8) = hi;
        __syncthreads();

        // B fragments for this k (issued first -> earlier vmcnt slot)
        v8s bf[4];
#pragma unroll
        for (int ni = 0; ni < 4; ++ni)
            bf[ni] = *(const v8s*)(wbase + (size_t)(ni * 16) * Kdim + k0);

        // A-chunk prefetch for next iteration (stays in flight through MFMA)
        if (k0 + 32 < Kdim) {
            const float* np = sbase + k0 + 32;
            f0 = *(const v4f*)np;
            f1 = *(const v4f*)(np + 4);
            f2v = *(const v4f*)(np + 8);
            f3 = *(const v4f*)(np + 12);
        }

        v8s a[4];
#pragma unroll
        for (int mi = 0; mi < 4; ++mi)
            a[mi] = *(const v8s*)(As + (wm0 + mi * 16 + col) * ASTRIDE + quad * 8);
#pragma unroll
        for (int mi = 0; mi < 4; ++mi)
#pragma unroll
            for (int ni = 0; ni < 4; ++ni)
                acc[mi][ni] = __builtin_amdgcn_mfma_f32_16x16x32_bf16(a[mi], bf[ni], acc[mi][ni], 0, 0, 0);
    }

    // epilogue: bias + store + fused column stats (sum / sumsq over rows)
#pragma unroll
    for (int ni = 0; ni < 4; ++ni) {
        const int n = bn0 + wn0 + ni * 16 + col;
        const float bv = bias[n];
        float s = 0.f, q = 0.f;
#pragma unroll
        for (int mi = 0; mi < 4; ++mi) {
            const int m = bm0 + wm0 + mi * 16 + quad * 4;
#pragma unroll
            for (int r = 0; r < 4; ++r) {
                const float y = acc[mi][ni][r] + bv;
                Y[(size_t)(m + r) * CC + n] = y;
                s += y; q += y * y;
            }
        }
        s += __shfl_xor(s, 16); q += __shfl_xor(q, 16);
        s += __shfl_xor(s, 32); q += __shfl_xor(q, 32);
        if (quad == 0) { atomicAdd(&sum[n], s); atomicAdd(&sumsq[n], q); }
    }
}

// ---------------------------------------------------------------------------
// Finalize BN constants: a = g*rsqrt(var+eps), c = beta - a*mu
// ---------------------------------------------------------------------------
__global__ __launch_bounds__(512)
void finalize_kernel(const float* __restrict__ sums,
                     const float* __restrict__ g1, const float* __restrict__ be1,
                     const float* __restrict__ g2, const float* __restrict__ be2,
                     float* __restrict__ ac)
{
    const int t = threadIdx.x;           // 0..511
    const int c = t & 255;
    const int which = t >> 8;            // 0: BN1, 1: BN2
    const float* s = sums + which * 512;
    const double n = which ? (double)N2R : (double)N1R;
    const double mu = (double)s[c] / n;
    const double var = (double)s[c + 256] / n - mu * mu;
    const float g  = which ? g2[c]  : g1[c];
    const float be = which ? be2[c] : be1[c];
    const double a  = (double)g / sqrt(var + 1e-5);
    const double cv = (double)be - a * mu;
    ac[which * 512 + c]       = (float)a;
    ac[which * 512 + 256 + c] = (float)cv;
}

// ---------------------------------------------------------------------------
// Grid KNN: cell-sorted queries scan their 27-cell neighborhood against the
// batch's cell-sorted points staged in LDS.  Exact fp32 distances
// (bit-matching the reference); lexicographic (d, idx) top-3.  Coverage:
// every point within 0.125 of q lies inside the clamped 27-cell block, so
// b2 < 0.125^2 certifies exactness; else brute-force fallback.
// Block: 256 thr = 128 queries x 2 half-scans (cells 0..13 / 14..26).
// ---------------------------------------------------------------------------
__global__ __launch_bounds__(256)
void knn_grid_kernel(const float* __restrict__ p1,
                     const float4* __restrict__ sortedP,
                     const unsigned short* __restrict__ sIdx16,
                     const int* __restrict__ starts_p,
                     const unsigned short* __restrict__ qlist,
                     int* __restrict__ idx_out, float* __restrict__ w_out,
                     int* __restrict__ failCount, int* __restrict__ failList)
{
#pragma clang fp contract(off)
    __shared__ float4 sP[NPB];                 // 64 KB
    __shared__ unsigned short sI[NPB];         // 8 KB
    __shared__ int sS[513];                    // 2 KB
    __shared__ float mD[128 * 3];              // 1.5 KB
    __shared__ int   mI[128 * 3];              // 1.5 KB

    const int b = blockIdx.x >> 7;             // 128 blocks per batch
    const int slot0 = (blockIdx.x & 127) * 128;
    const int tid = threadIdx.x;
    const int lq = tid & 127;                  // query slot within block
    const int half = tid >> 7;

    // stage the batch's cell-sorted points + idx + starts
    {
        const float4* gp = sortedP + (size_t)b * NPB;
        for (int i = tid; i < NPB; i += 256) sP[i] = gp[i];
        const unsigned int* gi = (const unsigned int*)(sIdx16 + (size_t)b * NPB);
        unsigned int* li = (unsigned int*)sI;
        for (int i = tid; i < NPB / 2; i += 256) li[i] = gi[i];
        const int* gs = starts_p + b * 513;
        for (int i = tid; i < 513; i += 256) sS[i] = gs[i];
    }

    const int q = qlist[(size_t)b * NQB + slot0 + lq];   // batch-local query id
    const int qid = b * NQB + q;
    const float qx = p1[(size_t)qid * 3 + 0];
    const float qy = p1[(size_t)qid * 3 + 1];
    const float qz = p1[(size_t)qid * 3 + 2];
    const float qq = (qx * qx + qy * qy) + qz * qz;
    const int cqx = min(7, (int)(qx * 8.0f));
    const int cqy = min(7, (int)(qy * 8.0f));
    const int cqz = min(7, (int)(qz * 8.0f));

    __syncthreads();

    float b0 = 3.0e38f, b1 = 3.0e38f, b2 = 3.0e38f;
    int i0 = 0x7fffffff, i1 = 0x7fffffff, i2 = 0x7fffffff;

    int n = 0;
    for (int dz = -1; dz <= 1; ++dz)
        for (int dy = -1; dy <= 1; ++dy)
            for (int dx = -1; dx <= 1; ++dx, ++n) {
                if (half ? (n < 14) : (n >= 14)) continue;   // 14 / 13 cell split
                const int cz = cqz + dz, cy = cqy + dy, cx = cqx + dx;
                if (((unsigned)cz | (unsigned)cy | (unsigned)cx) > 7u) continue;
                const int cell = (cz << 6) | (cy << 3) | cx;
                const int ks = sS[cell], ke = sS[cell + 1];
                for (int k = ks; k < ke; ++k) {
                    const float4 P = sP[k];
                    const int si = sI[k];
                    const float dot = fmaf(qz, P.z, fmaf(qy, P.y, qx * P.x));
                    const float d = fmaf(-2.0f, dot, qq + P.w);
                    ins3(d, si, b0, b1, b2, i0, i1, i2);
                }
            }

    if (half) {
        mD[lq * 3 + 0] = b0; mD[lq * 3 + 1] = b1; mD[lq * 3 + 2] = b2;
        mI[lq * 3 + 0] = i0; mI[lq * 3 + 1] = i1; mI[lq * 3 + 2] = i2;
    }
    __syncthreads();
    if (!half) {
#pragma unroll
        for (int r = 0; r < 3; ++r)
            ins3(mD[lq * 3 + r], mI[lq * 3 + r], b0, b1, b2, i0, i1, i2);

        if (!(b2 < GRID_FAIL_R2)) {            // includes <3-found case (b2=3e38)
            const int p = atomicAdd(failCount, 1);
            if (p < N1R) failList[p] = qid;    // capacity-exact; guard is free
        }
        const float r0 = 1.0f / (fmaxf(b0, 0.0f) + 1e-8f);
        const float r1 = 1.0f / (fmaxf(b1, 0.0f) + 1e-8f);
        const float r2 = 1.0f / (fmaxf(b2, 0.0f) + 1e-8f);
        const float rs = (r0 + r1) + r2;
        idx_out[(size_t)qid * 3 + 0] = i0;
        idx_out[(size_t)qid * 3 + 1] = i1;
        idx_out[(size_t)qid * 3 + 2] = i2;
        w_out[(size_t)qid * 3 + 0] = r0 / rs;
        w_out[(size_t)qid * 3 + 1] = r1 / rs;
        w_out[(size_t)qid * 3 + 2] = r2 / rs;
    }
}

// ---------------------------------------------------------------------------
// Brute-force fallback: one wave per failed query, lanes split 4096 points,
// butterfly shuffle-merge of per-lane top-3 triples.  Exact, tiny workload.
// ---------------------------------------------------------------------------
__global__ __launch_bounds__(256)
void knn_bf_kernel(const float* __restrict__ p1,
                   const float4* __restrict__ paug,
                   const int* __restrict__ failCount,
                   const int* __restrict__ failList,
                   int* __restrict__ idx_out, float* __restrict__ w_out)
{
#pragma clang fp contract(off)
    const int nf = min(*failCount, N1R);
    const int gw = (blockIdx.x * 256 + threadIdx.x) >> 6;
    const int lane = threadIdx.x & 63;
    const int nw = (gridDim.x * 256) >> 6;

    for (int fi = gw; fi < nf; fi += nw) {
        const int qid = failList[fi];
        const int b = qid >> 14;
        const float qx = p1[(size_t)qid * 3 + 0];
        const float qy = p1[(size_t)qid * 3 + 1];
        const float qz = p1[(size_t)qid * 3 + 2];
        const float qq = (qx * qx + qy * qy) + qz * qz;

        float b0 = 3.0e38f, b1 = 3.0e38f, b2 = 3.0e38f;
        int i0 = 0x7fffffff, i1 = 0x7fffffff, i2 = 0x7fffffff;

        const float4* pb = paug + (size_t)b * NPB;
        for (int j = lane; j < NPB; j += 64) {
            const float4 P = pb[j];
            const float dot = fmaf(qz, P.z, fmaf(qy, P.y, qx * P.x));
            const float d = fmaf(-2.0f, dot, qq + P.w);
            ins3(d, j, b0, b1, b2, i0, i1, i2);
        }
        // butterfly merge across the wave
        for (int m = 1; m < 64; m <<= 1) {
            const float c0 = __shfl_xor(b0, m), c1 = __shfl_xor(b1, m), c2 = __shfl_xor(b2, m);
            const int j0 = __shfl_xor(i0, m), j1 = __shfl_xor(i1, m), j2 = __shfl_xor(i2, m);
            ins3(c0, j0, b0, b1, b2, i0, i1, i2);
            ins3(c1, j1, b0, b1, b2, i0, i1, i2);
            ins3(c2, j2, b0, b1, b2, i0, i1, i2);
        }
        if (lane == 0) {
            const float r0 = 1.0f / (fmaxf(b0, 0.0f) + 1e-8f);
            const float r1 = 1.0f / (fmaxf(b1, 0.0f) + 1e-8f);
            const float r2 = 1.0f / (fmaxf(b2, 0.0f) + 1e-8f);
            const float rs = (r0 + r1) + r2;
            idx_out[(size_t)qid * 3 + 0] = i0;
            idx_out[(size_t)qid * 3 + 1] = i1;
            idx_out[(size_t)qid * 3 + 2] = i2;
            w_out[(size_t)qid * 3 + 0] = r0 / rs;
            w_out[(size_t)qid * 3 + 1] = r1 / rs;
            w_out[(size_t)qid * 3 + 2] = r2 / rs;
        }
    }
}

// ---------------------------------------------------------------------------
// Final: out[r][c] = relu(a1*Y1+c1) + sum_k w_k * relu(a2*Y2[idx_k]+c2).
// BN+ReLU of f2 fused into the gather (Y2 stays raw; bnrelu pass removed).
// ---------------------------------------------------------------------------
__global__ __launch_bounds__(256)
void final_kernel(float* __restrict__ Y1out,
                  const float* __restrict__ Y2raw,
                  const float* __restrict__ ac,        // a1,c1,a2,c2 (256 each)
                  const int* __restrict__ idx, const float* __restrict__ w)
{
    const int r = blockIdx.x * 4 + (threadIdx.x >> 6);
    const int cg = threadIdx.x & 63;
    const int b = r >> 14;

    v4f a1 = *(const v4f*)(ac + cg * 4);
    v4f c1 = *(const v4f*)(ac + 256 + cg * 4);
    v4f a2 = *(const v4f*)(ac + 512 + cg * 4);
    v4f c2 = *(const v4f*)(ac + 768 + cg * 4);
    v4f y = *(const v4f*)(Y1out + (size_t)r * CC + cg * 4);
    v4f s;
#pragma unroll
    for (int j = 0; j < 4; ++j)
        s[j] = fmaxf(fmaf(a1[j], y[j], c1[j]), 0.f);

    const int*   ir = idx + (size_t)r * 3;
    const float* wr = w   + (size_t)r * 3;
#pragma unroll
    for (int k = 0; k < 3; ++k) {
        const int id = ir[k];
        const float wk = wr[k];
        v4f g = *(const v4f*)(Y2raw + ((size_t)(b * NPB + id)) * CC + cg * 4);
#pragma unroll
        for (int j = 0; j < 4; ++j) {
            const float gv = fmaxf(fmaf(a2[j], g[j], c2[j]), 0.f);   // == bnrelu
            s[j] = fmaf(wk, gv, s[j]);
        }
    }
    *(v4f*)(Y1out + (size_t)r * CC + cg * 4) = s;
}

// ---------------------------------------------------------------------------
extern "C" void kernel_launch(void* const* d_in, const int* in_sizes, int n_in,
                              void* d_out, int out_size, void* d_ws, size_t ws_size,
                              hipStream_t stream)
{
    const float* point1 = (const float*)d_in[0];
    const float* feat1  = (const float*)d_in[1];
    const float* point2 = (const float*)d_in[2];
    const float* feat2  = (const float*)d_in[3];
    const float* W1     = (const float*)d_in[4];
    const float* b1     = (const float*)d_in[5];
    const float* g1     = (const float*)d_in[6];
    const float* beta1  = (const float*)d_in[7];
    const float* W2     = (const float*)d_in[8];
    const float* b2     = (const float*)d_in[9];
    const float* g2     = (const float*)d_in[10];
    const float* beta2  = (const float*)d_in[11];

    float* Y1 = (float*)d_out;                            // 64 MB (reused as output)

    char* ws = (char*)d_ws;
    float*          Y2       = (float*)ws;                                   // 16 MB (raw, BN fused in final)
    float*          stats    = (float*)(ws + (size_t)16777216);              // 4 KB
    int*            counts_p = (int*)  (ws + (size_t)16781312);              // 8 KB
    int*            counts_q = (int*)  (ws + (size_t)16789504);              // 8 KB
    int*            failCnt  = (int*)  (ws + (size_t)16797696);              // 4 KB pad
    int*            cursors_p= (int*)  (ws + (size_t)16801792);              // 8 KB
    int*            cursors_q= (int*)  (ws + (size_t)16809984);              // 8 KB
    int*            starts_p = (int*)  (ws + (size_t)16818176);              // 8.2 KB
    float*          ac       = (float*)(ws + (size_t)16826624);              // 4 KB
    unsigned short* sIdx16   = (unsigned short*)(ws + (size_t)16830720);     // 32 KB
    unsigned short* qlist    = (unsigned short*)(ws + (size_t)16863488);     // 128 KB
    int*            failList = (int*)  (ws + (size_t)16994560);              // 256 KB
    float4*         sortedP  = (float4*)(ws + (size_t)17256704);             // 256 KB
    int*            idxb     = (int*)  (ws + (size_t)17518848);              // 768 KB
    float*          wb       = (float*)(ws + (size_t)18305280);              // 768 KB
    short*          WT1      = (short*)(ws + (size_t)19091712);              // 128 KB
    short*          WT2      = (short*)(ws + (size_t)19222784);              // 256 KB
    float4*         paug     = (float4*)(ws + (size_t)19484928);             // 256 KB

    // zero: stats (4KB) + counts_p (8KB) + counts_q (8KB) + failCnt (4KB)
    hipMemsetAsync(stats, 0, 24576, stream);

    // Tiny prep kernels
    wtrans_kernel<<<256, 256, 0, stream>>>(W1, WT1, 256);
    wtrans_kernel<<<512, 256, 0, stream>>>(W2, WT2, 512);

    // Cell-grid build: histograms -> prefix/cursors -> scatters
    paug_count_kernel<<<N2R / 256, 256, 0, stream>>>(point2, paug, counts_p);
    qcount_kernel<<<N1R / 256, 256, 0, stream>>>(point1, counts_q);
    prefix_kernel<<<1, 512, 0, stream>>>(counts_p, cursors_p, starts_p, counts_q, cursors_q);
    scatter_p_kernel<<<N2R / 256, 256, 0, stream>>>(paug, cursors_p, sortedP, sIdx16);
    scatter_q_kernel<<<N1R / 256, 256, 0, stream>>>(point1, cursors_q, qlist);

    // Fused GEMM + BN stats (round-2 K-loop): grid = (rows/128, 256/128)
    gemm_fused_kernel<<<dim3(N1R / 128, 2), 256, 0, stream>>>(feat1, WT1, b1, Y1,
                                                              stats + 0,   stats + 256, 256);
    gemm_fused_kernel<<<dim3(N2R / 128, 2), 256, 0, stream>>>(feat2, WT2, b2, Y2,
                                                              stats + 512, stats + 768, 512);

    finalize_kernel<<<1, 512, 0, stream>>>(stats, g1, beta1, g2, beta2, ac);

    // Grid KNN (exact) + brute-force fallback for boundary failures
    knn_grid_kernel<<<512, 256, 0, stream>>>(point1, sortedP, sIdx16, starts_p,
                                             qlist, idxb, wb, failCnt, failList);
    knn_bf_kernel<<<256, 256, 0, stream>>>(point1, paug, failCnt, failList, idxb, wb);

    // out = relu(bn(Y1)) + weighted gather of relu(bn(Y2))  (in-place on d_out)
    final_kernel<<<N1R / 4, 256, 0, stream>>>(Y1, Y2, ac, idxb, wb);
}

// Round 6
// 319.803 us; speedup vs baseline: 1.1423x; 1.0805x over previous
//
#include <hip/hip_runtime.h>
#include <hip/hip_bf16.h>
#include <math.h>

// Problem constants
#define N1R 65536   // B*N1 query rows
#define N2R 16384   // B*N2 point rows
#define NPB 4096    // N2 per batch
#define NQB 16384   // N1 per batch
#define CC  256     // COUT
#define ASTRIDE 40  // LDS A-tile row stride in bf16 elems (80B: 16B-aligned, ~2-way banks)
#define NCELL 512   // 8x8x8 grid cells per batch
#define GRID_FAIL_R2 0.015625f   // (1/8)^2 coverage bound of the 27-cell block

typedef __attribute__((ext_vector_type(4))) float v4f;
typedef __attribute__((ext_vector_type(8))) short v8s;

static __device__ __forceinline__ short f2bs(float f) {
    union { __hip_bfloat16 h; short s; } u;
    u.h = __float2bfloat16(f);
    return u.s;
}

static __device__ __forceinline__ int cell_of(float x, float y, float z) {
    const int cx = min(7, (int)(x * 8.0f));
    const int cy = min(7, (int)(y * 8.0f));
    const int cz = min(7, (int)(z * 8.0f));
    return (cz << 6) | (cy << 3) | cx;
}

// branchless lexicographic (d, idx) top-3 insert; keeps b0<=b1<=b2 sorted
static __device__ __forceinline__ void ins3(float d, int si,
    float& b0, float& b1, float& b2, int& i0, int& i1, int& i2)
{
    const bool lt0 = (d < b0) | ((d == b0) & (si < i0));
    const bool lt1 = (d < b1) | ((d == b1) & (si < i1));
    const bool lt2 = (d < b2) | ((d == b2) & (si < i2));
    b2 = lt1 ? b1 : (lt2 ? d : b2);   i2 = lt1 ? i1 : (lt2 ? si : i2);
    b1 = lt0 ? b0 : (lt1 ? d : b1);   i1 = lt0 ? i0 : (lt1 ? si : i1);
    b0 = lt0 ? d  : b0;               i0 = lt0 ? si : i0;
}

// ---------------------------------------------------------------------------
// W transpose + bf16 convert: WT[n][k] = bf16(W[k][n]).  W: Kd x 256.
// ---------------------------------------------------------------------------
__global__ __launch_bounds__(256)
void wtrans_kernel(const float* __restrict__ W, short* __restrict__ WT, int Kd)
{
    const int i = blockIdx.x * 256 + threadIdx.x;   // over Kd*256
    const int k = i >> 8;
    const int n = i & 255;
    WT[(size_t)n * Kd + k] = f2bs(W[i]);
}

// ---------------------------------------------------------------------------
// Point augmentation + cell histogram: paug[i] = {x, y, z, (x*x+y*y)+z*z}
// (exact fp32, no FMA — bit-matches the reference's pp computation).
// ---------------------------------------------------------------------------
__global__ __launch_bounds__(256)
void paug_count_kernel(const float* __restrict__ p2, float4* __restrict__ paug,
                       int* __restrict__ counts_p)
{
#pragma clang fp contract(off)
    const int i = blockIdx.x * 256 + threadIdx.x;   // over N2R
    const float x = p2[(size_t)i * 3 + 0];
    const float y = p2[(size_t)i * 3 + 1];
    const float z = p2[(size_t)i * 3 + 2];
    float4 v;
    v.x = x; v.y = y; v.z = z;
    v.w = (x * x + y * y) + z * z;
    paug[i] = v;
    const int b = i >> 12;                // 4096 points per batch
    atomicAdd(&counts_p[b * NCELL + cell_of(x, y, z)], 1);
}

// ---------------------------------------------------------------------------
// Query cell histogram.
// ---------------------------------------------------------------------------
__global__ __launch_bounds__(256)
void qcount_kernel(const float* __restrict__ p1, int* __restrict__ counts_q)
{
    const int i = blockIdx.x * 256 + threadIdx.x;   // over N1R
    const float x = p1[(size_t)i * 3 + 0];
    const float y = p1[(size_t)i * 3 + 1];
    const float z = p1[(size_t)i * 3 + 2];
    const int b = i >> 14;                // 16384 queries per batch
    atomicAdd(&counts_q[b * NCELL + cell_of(x, y, z)], 1);
}

// ---------------------------------------------------------------------------
// Exclusive prefix over 512 cells, 4 batches x {points, queries}.
// Writes starts_p (with 513th sentinel) and initializes scatter cursors.
// ---------------------------------------------------------------------------
__global__ __launch_bounds__(512)
void prefix_kernel(const int* __restrict__ counts_p, int* __restrict__ cursors_p,
                   int* __restrict__ starts_p,
                   const int* __restrict__ counts_q, int* __restrict__ cursors_q)
{
    __shared__ int sc[512];
    const int t = threadIdx.x;
    for (int a = 0; a < 8; ++a) {
        const int b = a & 3;
        const int* cnt = (a < 4) ? counts_p + b * NCELL : counts_q + b * NCELL;
        const int v = cnt[t];
        sc[t] = v;
        __syncthreads();
        for (int off = 1; off < 512; off <<= 1) {
            const int add = (t >= off) ? sc[t - off] : 0;
            __syncthreads();
            sc[t] += add;
            __syncthreads();
        }
        const int incl = sc[t];
        const int excl = incl - v;
        if (a < 4) {
            starts_p[b * 513 + t] = excl;
            if (t == 511) starts_p[b * 513 + 512] = incl;   // == 4096
            cursors_p[b * NCELL + t] = excl;
        } else {
            cursors_q[b * NCELL + t] = excl;
        }
        __syncthreads();
    }
}

// ---------------------------------------------------------------------------
// Scatter points into cell-sorted order (batch-relative), keep original idx.
// ---------------------------------------------------------------------------
__global__ __launch_bounds__(256)
void scatter_p_kernel(const float4* __restrict__ paug, int* __restrict__ cursors,
                      float4* __restrict__ sortedP, unsigned short* __restrict__ sIdx)
{
    const int i = blockIdx.x * 256 + threadIdx.x;   // over N2R
    const float4 v = paug[i];
    const int b = i >> 12;
    const int cell = cell_of(v.x, v.y, v.z);
    const int pos = atomicAdd(&cursors[b * NCELL + cell], 1);
    sortedP[(size_t)b * NPB + pos] = v;
    sIdx[(size_t)b * NPB + pos] = (unsigned short)(i & 4095);
}

// ---------------------------------------------------------------------------
// Scatter queries into cell-sorted order (batch-local u16 ids).
// ---------------------------------------------------------------------------
__global__ __launch_bounds__(256)
void scatter_q_kernel(const float* __restrict__ p1, int* __restrict__ cursors,
                      unsigned short* __restrict__ qlist)
{
    const int i = blockIdx.x * 256 + threadIdx.x;   // over N1R
    const float x = p1[(size_t)i * 3 + 0];
    const float y = p1[(size_t)i * 3 + 1];
    const float z = p1[(size_t)i * 3 + 2];
    const int b = i >> 14;
    const int cell = cell_of(x, y, z);
    const int pos = atomicAdd(&cursors[b * NCELL + cell], 1);
    qlist[(size_t)b * NQB + pos] = (unsigned short)(i & 16383);
}

// ---------------------------------------------------------------------------
// Fused tiled GEMM + column-stat PARTIALS: Y = X @ WT^T + bias, plus
// non-atomic per-(block, wave-m-row) column sum/sumsq partial writes.
// K-loop is the round-2 proven structure (55.5 us @ KD=256).
// Partial layout: row = blockIdx.x*2 + (wave>>1); each row has 256 cols;
// the two y-blocks / the two n-waves write disjoint column ranges -> no
// races, no atomics (round-5 lesson: 524K atomics on 512 addrs cost ~30us).
// ---------------------------------------------------------------------------
__global__ __launch_bounds__(256)
void gemm_fused_kernel(const float* __restrict__ X,
                       const short* __restrict__ WT,
                       const float* __restrict__ bias,
                       float* __restrict__ Y,
                       float* __restrict__ partS, float* __restrict__ partQ,
                       int Kdim)
{
    __shared__ short As[128 * ASTRIDE];

    const int bm0 = blockIdx.x * 128;
    const int bn0 = blockIdx.y * 128;
    const int wave = threadIdx.x >> 6;
    const int lane = threadIdx.x & 63;
    const int wm0 = (wave >> 1) * 64;
    const int wn0 = (wave & 1) * 64;
    const int col = lane & 15, quad = lane >> 4;

    const int srow = threadIdx.x >> 1;
    const int skh  = (threadIdx.x & 1) * 16;
    const float* sbase = X + (size_t)(bm0 + srow) * Kdim + skh;
    short* sdst = As + srow * ASTRIDE + skh;

    v4f acc[4][4];
#pragma unroll
    for (int i = 0; i < 4; ++i)
#pragma unroll
        for (int j = 0; j < 4; ++j) acc[i][j] = (v4f){0.f, 0.f, 0.f, 0.f};

    const short* wbase = WT + (size_t)(bn0 + wn0 + col) * Kdim + quad * 8;

    // prologue A prefetch
    v4f f0 = *(const v4f*)(sbase);
    v4f f1 = *(const v4f*)(sbase + 4);
    v4f f2v = *(const v4f*)(sbase + 8);
    v4f f3 = *(const v4f*)(sbase + 12);

    for (int k0 = 0; k0 < Kdim; k0 += 32) {
        v8s lo, hi;
#pragma unroll
        for (int j = 0; j < 4; ++j) {
            lo[j] = f2bs(f0[j]); lo[j + 4] = f2bs(f1[j]);
            hi[j] = f2bs(f2v[j]); hi[j + 4] = f2bs(f3[j]);
        }
        __syncthreads();   // previous iteration's LDS reads complete
        *(v8s*)sdst = lo;
        *(v8s*)(sdst + 8) = hi;
        __syncthreads();

        // B fragments for this k (issued first -> earlier vmcnt slot)
        v8s bf[4];
#pragma unroll
        for (int ni = 0; ni < 4; ++ni)
            bf[ni] = *(const v8s*)(wbase + (size_t)(ni * 16) * Kdim + k0);

        // A-chunk prefetch for next iteration (stays in flight through MFMA)
        if (k0 + 32 < Kdim) {
            const float* np = sbase + k0 + 32;
            f0 = *(const v4f*)np;
            f1 = *(const v4f*)(np + 4);
            f2v = *(const v4f*)(np + 8);
            f3 = *(const v4f*)(np + 12);
        }

        v8s a[4];
#pragma unroll
        for (int mi = 0; mi < 4; ++mi)
            a[mi] = *(const v8s*)(As + (wm0 + mi * 16 + col) * ASTRIDE + quad * 8);
#pragma unroll
        for (int mi = 0; mi < 4; ++mi)
#pragma unroll
            for (int ni = 0; ni < 4; ++ni)
                acc[mi][ni] = __builtin_amdgcn_mfma_f32_16x16x32_bf16(a[mi], bf[ni], acc[mi][ni], 0, 0, 0);
    }

    // epilogue: bias + store + non-atomic partial stats
    float* pS = partS + (size_t)(blockIdx.x * 2 + (wave >> 1)) * CC;
    float* pQ = partQ + (size_t)(blockIdx.x * 2 + (wave >> 1)) * CC;
#pragma unroll
    for (int ni = 0; ni < 4; ++ni) {
        const int n = bn0 + wn0 + ni * 16 + col;
        const float bv = bias[n];
        float s = 0.f, q = 0.f;
#pragma unroll
        for (int mi = 0; mi < 4; ++mi) {
            const int m = bm0 + wm0 + mi * 16 + quad * 4;
#pragma unroll
            for (int r = 0; r < 4; ++r) {
                const float y = acc[mi][ni][r] + bv;
                Y[(size_t)(m + r) * CC + n] = y;
                s += y; q += y * y;
            }
        }
        s += __shfl_xor(s, 16); q += __shfl_xor(q, 16);
        s += __shfl_xor(s, 32); q += __shfl_xor(q, 32);
        if (quad == 0) { pS[n] = s; pQ[n] = q; }
    }
}

// ---------------------------------------------------------------------------
// Partial-stat reduce: blocks 0..15 sum BN1's 1024 partial rows (64 each),
// blocks 16..19 sum BN2's 256 rows (64 each); ~10 atomics/address only.
// ---------------------------------------------------------------------------
__global__ __launch_bounds__(256)
void stat_reduce_kernel(const float* __restrict__ pS1, const float* __restrict__ pQ1,
                        const float* __restrict__ pS2, const float* __restrict__ pQ2,
                        float* __restrict__ stats)
{
    const int c = threadIdx.x;
    const bool two = blockIdx.x >= 16;
    const float* pS = two ? pS2 : pS1;
    const float* pQ = two ? pQ2 : pQ1;
    const int r0 = (two ? (blockIdx.x - 16) : blockIdx.x) * 64;
    float s = 0.f, q = 0.f;
    for (int r = r0; r < r0 + 64; ++r) {
        s += pS[(size_t)r * CC + c];
        q += pQ[(size_t)r * CC + c];
    }
    float* st = stats + (two ? 512 : 0);
    atomicAdd(&st[c], s);
    atomicAdd(&st[256 + c], q);
}

// ---------------------------------------------------------------------------
// Finalize BN constants: a = g*rsqrt(var+eps), c = beta - a*mu
// ---------------------------------------------------------------------------
__global__ __launch_bounds__(512)
void finalize_kernel(const float* __restrict__ sums,
                     const float* __restrict__ g1, const float* __restrict__ be1,
                     const float* __restrict__ g2, const float* __restrict__ be2,
                     float* __restrict__ ac)
{
    const int t = threadIdx.x;           // 0..511
    const int c = t & 255;
    const int which = t >> 8;            // 0: BN1, 1: BN2
    const float* s = sums + which * 512;
    const double n = which ? (double)N2R : (double)N1R;
    const double mu = (double)s[c] / n;
    const double var = (double)s[c + 256] / n - mu * mu;
    const float g  = which ? g2[c]  : g1[c];
    const float be = which ? be2[c] : be1[c];
    const double a  = (double)g / sqrt(var + 1e-5);
    const double cv = (double)be - a * mu;
    ac[which * 512 + c]       = (float)a;
    ac[which * 512 + 256 + c] = (float)cv;
}

// ---------------------------------------------------------------------------
// Grid KNN: cell-sorted queries scan their 27-cell neighborhood against the
// batch's cell-sorted points staged in LDS.  Exact fp32 distances
// (bit-matching the reference); lexicographic (d, idx) top-3.  Coverage:
// every point within 0.125 of q lies inside the clamped 27-cell block, so
// b2 < 0.125^2 certifies exactness; else brute-force fallback.
// Block: 256 thr = 128 queries x 2 half-scans (cells 0..13 / 14..26).
// ---------------------------------------------------------------------------
__global__ __launch_bounds__(256)
void knn_grid_kernel(const float* __restrict__ p1,
                     const float4* __restrict__ sortedP,
                     const unsigned short* __restrict__ sIdx16,
                     const int* __restrict__ starts_p,
                     const unsigned short* __restrict__ qlist,
                     int* __restrict__ idx_out, float* __restrict__ w_out,
                     int* __restrict__ failCount, int* __restrict__ failList)
{
#pragma clang fp contract(off)
    __shared__ float4 sP[NPB];                 // 64 KB
    __shared__ unsigned short sI[NPB];         // 8 KB
    __shared__ int sS[513];                    // 2 KB
    __shared__ float mD[128 * 3];              // 1.5 KB
    __shared__ int   mI[128 * 3];              // 1.5 KB

    const int b = blockIdx.x >> 7;             // 128 blocks per batch
    const int slot0 = (blockIdx.x & 127) * 128;
    const int tid = threadIdx.x;
    const int lq = tid & 127;                  // query slot within block
    const int half = tid >> 7;

    // stage the batch's cell-sorted points + idx + starts
    {
        const float4* gp = sortedP + (size_t)b * NPB;
        for (int i = tid; i < NPB; i += 256) sP[i] = gp[i];
        const unsigned int* gi = (const unsigned int*)(sIdx16 + (size_t)b * NPB);
        unsigned int* li = (unsigned int*)sI;
        for (int i = tid; i < NPB / 2; i += 256) li[i] = gi[i];
        const int* gs = starts_p + b * 513;
        for (int i = tid; i < 513; i += 256) sS[i] = gs[i];
    }

    const int q = qlist[(size_t)b * NQB + slot0 + lq];   // batch-local query id
    const int qid = b * NQB + q;
    const float qx = p1[(size_t)qid * 3 + 0];
    const float qy = p1[(size_t)qid * 3 + 1];
    const float qz = p1[(size_t)qid * 3 + 2];
    const float qq = (qx * qx + qy * qy) + qz * qz;
    const int cqx = min(7, (int)(qx * 8.0f));
    const int cqy = min(7, (int)(qy * 8.0f));
    const int cqz = min(7, (int)(qz * 8.0f));

    __syncthreads();

    float b0 = 3.0e38f, b1 = 3.0e38f, b2 = 3.0e38f;
    int i0 = 0x7fffffff, i1 = 0x7fffffff, i2 = 0x7fffffff;

    int n = 0;
    for (int dz = -1; dz <= 1; ++dz)
        for (int dy = -1; dy <= 1; ++dy)
            for (int dx = -1; dx <= 1; ++dx, ++n) {
                if (half ? (n < 14) : (n >= 14)) continue;   // 14 / 13 cell split
                const int cz = cqz + dz, cy = cqy + dy, cx = cqx + dx;
                if (((unsigned)cz | (unsigned)cy | (unsigned)cx) > 7u) continue;
                const int cell = (cz << 6) | (cy << 3) | cx;
                const int ks = sS[cell], ke = sS[cell + 1];
                for (int k = ks; k < ke; ++k) {
                    const float4 P = sP[k];
                    const int si = sI[k];
                    const float dot = fmaf(qz, P.z, fmaf(qy, P.y, qx * P.x));
                    const float d = fmaf(-2.0f, dot, qq + P.w);
                    ins3(d, si, b0, b1, b2, i0, i1, i2);
                }
            }

    if (half) {
        mD[lq * 3 + 0] = b0; mD[lq * 3 + 1] = b1; mD[lq * 3 + 2] = b2;
        mI[lq * 3 + 0] = i0; mI[lq * 3 + 1] = i1; mI[lq * 3 + 2] = i2;
    }
    __syncthreads();
    if (!half) {
#pragma unroll
        for (int r = 0; r < 3; ++r)
            ins3(mD[lq * 3 + r], mI[lq * 3 + r], b0, b1, b2, i0, i1, i2);

        if (!(b2 < GRID_FAIL_R2)) {            // includes <3-found case (b2=3e38)
            const int p = atomicAdd(failCount, 1);
            if (p < N1R) failList[p] = qid;    // capacity-exact; guard is free
        }
        const float r0 = 1.0f / (fmaxf(b0, 0.0f) + 1e-8f);
        const float r1 = 1.0f / (fmaxf(b1, 0.0f) + 1e-8f);
        const float r2 = 1.0f / (fmaxf(b2, 0.0f) + 1e-8f);
        const float rs = (r0 + r1) + r2;
        idx_out[(size_t)qid * 3 + 0] = i0;
        idx_out[(size_t)qid * 3 + 1] = i1;
        idx_out[(size_t)qid * 3 + 2] = i2;
        w_out[(size_t)qid * 3 + 0] = r0 / rs;
        w_out[(size_t)qid * 3 + 1] = r1 / rs;
        w_out[(size_t)qid * 3 + 2] = r2 / rs;
    }
}

// ---------------------------------------------------------------------------
// Brute-force fallback: one wave per failed query, lanes split 4096 points,
// butterfly shuffle-merge of per-lane top-3 triples.  Exact, tiny workload.
// ---------------------------------------------------------------------------
__global__ __launch_bounds__(256)
void knn_bf_kernel(const float* __restrict__ p1,
                   const float4* __restrict__ paug,
                   const int* __restrict__ failCount,
                   const int* __restrict__ failList,
                   int* __restrict__ idx_out, float* __restrict__ w_out)
{
#pragma clang fp contract(off)
    const int nf = min(*failCount, N1R);
    const int gw = (blockIdx.x * 256 + threadIdx.x) >> 6;
    const int lane = threadIdx.x & 63;
    const int nw = (gridDim.x * 256) >> 6;

    for (int fi = gw; fi < nf; fi += nw) {
        const int qid = failList[fi];
        const int b = qid >> 14;
        const float qx = p1[(size_t)qid * 3 + 0];
        const float qy = p1[(size_t)qid * 3 + 1];
        const float qz = p1[(size_t)qid * 3 + 2];
        const float qq = (qx * qx + qy * qy) + qz * qz;

        float b0 = 3.0e38f, b1 = 3.0e38f, b2 = 3.0e38f;
        int i0 = 0x7fffffff, i1 = 0x7fffffff, i2 = 0x7fffffff;

        const float4* pb = paug + (size_t)b * NPB;
        for (int j = lane; j < NPB; j += 64) {
            const float4 P = pb[j];
            const float dot = fmaf(qz, P.z, fmaf(qy, P.y, qx * P.x));
            const float d = fmaf(-2.0f, dot, qq + P.w);
            ins3(d, j, b0, b1, b2, i0, i1, i2);
        }
        // butterfly merge across the wave
        for (int m = 1; m < 64; m <<= 1) {
            const float c0 = __shfl_xor(b0, m), c1 = __shfl_xor(b1, m), c2 = __shfl_xor(b2, m);
            const int j0 = __shfl_xor(i0, m), j1 = __shfl_xor(i1, m), j2 = __shfl_xor(i2, m);
            ins3(c0, j0, b0, b1, b2, i0, i1, i2);
            ins3(c1, j1, b0, b1, b2, i0, i1, i2);
            ins3(c2, j2, b0, b1, b2, i0, i1, i2);
        }
        if (lane == 0) {
            const float r0 = 1.0f / (fmaxf(b0, 0.0f) + 1e-8f);
            const float r1 = 1.0f / (fmaxf(b1, 0.0f) + 1e-8f);
            const float r2 = 1.0f / (fmaxf(b2, 0.0f) + 1e-8f);
            const float rs = (r0 + r1) + r2;
            idx_out[(size_t)qid * 3 + 0] = i0;
            idx_out[(size_t)qid * 3 + 1] = i1;
            idx_out[(size_t)qid * 3 + 2] = i2;
            w_out[(size_t)qid * 3 + 0] = r0 / rs;
            w_out[(size_t)qid * 3 + 1] = r1 / rs;
            w_out[(size_t)qid * 3 + 2] = r2 / rs;
        }
    }
}

// ---------------------------------------------------------------------------
// Final: out[r][c] = relu(a1*Y1+c1) + sum_k w_k * relu(a2*Y2[idx_k]+c2).
// BN+ReLU of f2 fused into the gather (Y2 stays raw; bnrelu pass removed).
// ---------------------------------------------------------------------------
__global__ __launch_bounds__(256)
void final_kernel(float* __restrict__ Y1out,
                  const float* __restrict__ Y2raw,
                  const float* __restrict__ ac,        // a1,c1,a2,c2 (256 each)
                  const int* __restrict__ idx, const float* __restrict__ w)
{
    const int r = blockIdx.x * 4 + (threadIdx.x >> 6);
    const int cg = threadIdx.x & 63;
    const int b = r >> 14;

    v4f a1 = *(const v4f*)(ac + cg * 4);
    v4f c1 = *(const v4f*)(ac + 256 + cg * 4);
    v4f a2 = *(const v4f*)(ac + 512 + cg * 4);
    v4f c2 = *(const v4f*)(ac + 768 + cg * 4);
    v4f y = *(const v4f*)(Y1out + (size_t)r * CC + cg * 4);
    v4f s;
#pragma unroll
    for (int j = 0; j < 4; ++j)
        s[j] = fmaxf(fmaf(a1[j], y[j], c1[j]), 0.f);

    const int*   ir = idx + (size_t)r * 3;
    const float* wr = w   + (size_t)r * 3;
#pragma unroll
    for (int k = 0; k < 3; ++k) {
        const int id = ir[k];
        const float wk = wr[k];
        v4f g = *(const v4f*)(Y2raw + ((size_t)(b * NPB + id)) * CC + cg * 4);
#pragma unroll
        for (int j = 0; j < 4; ++j) {
            const float gv = fmaxf(fmaf(a2[j], g[j], c2[j]), 0.f);   // == bnrelu
            s[j] = fmaf(wk, gv, s[j]);
        }
    }
    *(v4f*)(Y1out + (size_t)r * CC + cg * 4) = s;
}

// ---------------------------------------------------------------------------
extern "C" void kernel_launch(void* const* d_in, const int* in_sizes, int n_in,
                              void* d_out, int out_size, void* d_ws, size_t ws_size,
                              hipStream_t stream)
{
    const float* point1 = (const float*)d_in[0];
    const float* feat1  = (const float*)d_in[1];
    const float* point2 = (const float*)d_in[2];
    const float* feat2  = (const float*)d_in[3];
    const float* W1     = (const float*)d_in[4];
    const float* b1     = (const float*)d_in[5];
    const float* g1     = (const float*)d_in[6];
    const float* beta1  = (const float*)d_in[7];
    const float* W2     = (const float*)d_in[8];
    const float* b2     = (const float*)d_in[9];
    const float* g2     = (const float*)d_in[10];
    const float* beta2  = (const float*)d_in[11];

    float* Y1 = (float*)d_out;                            // 64 MB (reused as output)

    char* ws = (char*)d_ws;
    float*          Y2       = (float*)ws;                                   // 16 MB (raw, BN fused in final)
    float*          stats    = (float*)(ws + (size_t)16777216);              // 4 KB
    int*            counts_p = (int*)  (ws + (size_t)16781312);              // 8 KB
    int*            counts_q = (int*)  (ws + (size_t)16789504);              // 8 KB
    int*            failCnt  = (int*)  (ws + (size_t)16797696);              // 4 KB pad
    int*            cursors_p= (int*)  (ws + (size_t)16801792);              // 8 KB
    int*            cursors_q= (int*)  (ws + (size_t)16809984);              // 8 KB
    int*            starts_p = (int*)  (ws + (size_t)16818176);              // 8.2 KB
    float*          ac       = (float*)(ws + (size_t)16826624);              // 4 KB
    unsigned short* sIdx16   = (unsigned short*)(ws + (size_t)16830720);     // 32 KB
    unsigned short* qlist    = (unsigned short*)(ws + (size_t)16863488);     // 128 KB
    int*            failList = (int*)  (ws + (size_t)16994560);              // 256 KB
    float4*         sortedP  = (float4*)(ws + (size_t)17256704);             // 256 KB
    int*            idxb     = (int*)  (ws + (size_t)17518848);              // 768 KB
    float*          wb       = (float*)(ws + (size_t)18305280);              // 768 KB
    short*          WT1      = (short*)(ws + (size_t)19091712);              // 128 KB
    short*          WT2      = (short*)(ws + (size_t)19222784);              // 256 KB
    float4*         paug     = (float4*)(ws + (size_t)19484928);             // 256 KB
    float*          partS1   = (float*)(ws + (size_t)19747072);              // 1 MB (1024 x 256)
    float*          partQ1   = (float*)(ws + (size_t)20795648);              // 1 MB
    float*          partS2   = (float*)(ws + (size_t)21844224);              // 256 KB (256 x 256)
    float*          partQ2   = (float*)(ws + (size_t)22106368);              // 256 KB

    // zero: stats (4KB) + counts_p (8KB) + counts_q (8KB) + failCnt (4KB)
    hipMemsetAsync(stats, 0, 24576, stream);

    // Tiny prep kernels
    wtrans_kernel<<<256, 256, 0, stream>>>(W1, WT1, 256);
    wtrans_kernel<<<512, 256, 0, stream>>>(W2, WT2, 512);

    // Cell-grid build: histograms -> prefix/cursors -> scatters
    paug_count_kernel<<<N2R / 256, 256, 0, stream>>>(point2, paug, counts_p);
    qcount_kernel<<<N1R / 256, 256, 0, stream>>>(point1, counts_q);
    prefix_kernel<<<1, 512, 0, stream>>>(counts_p, cursors_p, starts_p, counts_q, cursors_q);
    scatter_p_kernel<<<N2R / 256, 256, 0, stream>>>(paug, cursors_p, sortedP, sIdx16);
    scatter_q_kernel<<<N1R / 256, 256, 0, stream>>>(point1, cursors_q, qlist);

    // Fused GEMM + non-atomic stat partials: grid = (rows/128, 256/128)
    gemm_fused_kernel<<<dim3(N1R / 128, 2), 256, 0, stream>>>(feat1, WT1, b1, Y1,
                                                              partS1, partQ1, 256);
    gemm_fused_kernel<<<dim3(N2R / 128, 2), 256, 0, stream>>>(feat2, WT2, b2, Y2,
                                                              partS2, partQ2, 512);

    // Partial reduce (16 blocks BN1 + 4 blocks BN2) then finalize
    stat_reduce_kernel<<<20, 256, 0, stream>>>(partS1, partQ1, partS2, partQ2, stats);
    finalize_kernel<<<1, 512, 0, stream>>>(stats, g1, beta1, g2, beta2, ac);

    // Grid KNN (exact) + brute-force fallback for boundary failures
    knn_grid_kernel<<<512, 256, 0, stream>>>(point1, sortedP, sIdx16, starts_p,
                                             qlist, idxb, wb, failCnt, failList);
    knn_bf_kernel<<<256, 256, 0, stream>>>(point1, paug, failCnt, failList, idxb, wb);

    // out = relu(bn(Y1)) + weighted gather of relu(bn(Y2))  (in-place on d_out)
    final_kernel<<<N1R / 4, 256, 0, stream>>>(Y1, Y2, ac, idxb, wb);
}

// Round 7
// 315.405 us; speedup vs baseline: 1.1583x; 1.0139x over previous
//
#include <hip/hip_runtime.h>
#include <hip/hip_bf16.h>
#include <math.h>

// Problem constants
#define N1R 65536   // B*N1 query rows
#define N2R 16384   // B*N2 point rows
#define NPB 4096    // N2 per batch
#define NQB 16384   // N1 per batch
#define CC  256     // COUT
#define ASTRIDE 40  // LDS A-tile row stride in bf16 elems (80B: 16B-aligned, ~2-way banks)
#define NCELL 512   // 8x8x8 grid cells per batch
#define GRID_FAIL_R2 0.015625f   // (1/8)^2 coverage bound of the 27-cell block

typedef __attribute__((ext_vector_type(4))) float v4f;
typedef __attribute__((ext_vector_type(8))) short v8s;

static __device__ __forceinline__ short f2bs(float f) {
    union { __hip_bfloat16 h; short s; } u;
    u.h = __float2bfloat16(f);
    return u.s;
}

static __device__ __forceinline__ int cell_of(float x, float y, float z) {
    const int cx = min(7, (int)(x * 8.0f));
    const int cy = min(7, (int)(y * 8.0f));
    const int cz = min(7, (int)(z * 8.0f));
    return (cz << 6) | (cy << 3) | cx;
}

// branchless lexicographic (d, idx) top-3 insert; keeps b0<=b1<=b2 sorted
static __device__ __forceinline__ void ins3(float d, int si,
    float& b0, float& b1, float& b2, int& i0, int& i1, int& i2)
{
    const bool lt0 = (d < b0) | ((d == b0) & (si < i0));
    const bool lt1 = (d < b1) | ((d == b1) & (si < i1));
    const bool lt2 = (d < b2) | ((d == b2) & (si < i2));
    b2 = lt1 ? b1 : (lt2 ? d : b2);   i2 = lt1 ? i1 : (lt2 ? si : i2);
    b1 = lt0 ? b0 : (lt1 ? d : b1);   i1 = lt0 ? i0 : (lt1 ? si : i1);
    b0 = lt0 ? d  : b0;               i0 = lt0 ? si : i0;
}

// ---------------------------------------------------------------------------
// W transposes (both weights in one launch): WT[n][k] = bf16(W[k][n]).
// ---------------------------------------------------------------------------
__global__ __launch_bounds__(256)
void wtrans_all_kernel(const float* __restrict__ W1f, const float* __restrict__ W2f,
                       short* __restrict__ WT1, short* __restrict__ WT2)
{
    const int i = blockIdx.x * 256 + threadIdx.x;   // 0 .. 196607
    if (i < 65536) {
        const int k = i >> 8, n = i & 255;
        WT1[(size_t)n * 256 + k] = f2bs(W1f[i]);
    } else {
        const int j = i - 65536;
        const int k = j >> 8, n = j & 255;
        WT2[(size_t)n * 512 + k] = f2bs(W2f[j]);
    }
}

// ---------------------------------------------------------------------------
// Point aug + both cell histograms in one launch.
// blocks 0..63: points (paug = {x,y,z,(x*x+y*y)+z*z}, exact fp32 no FMA);
// blocks 64..319: query histogram.
// ---------------------------------------------------------------------------
__global__ __launch_bounds__(256)
void hist_kernel(const float* __restrict__ p2, const float* __restrict__ p1,
                 float4* __restrict__ paug,
                 int* __restrict__ counts_p, int* __restrict__ counts_q)
{
#pragma clang fp contract(off)
    if (blockIdx.x < 64) {
        const int i = blockIdx.x * 256 + threadIdx.x;   // over N2R
        const float x = p2[(size_t)i * 3 + 0];
        const float y = p2[(size_t)i * 3 + 1];
        const float z = p2[(size_t)i * 3 + 2];
        float4 v;
        v.x = x; v.y = y; v.z = z;
        v.w = (x * x + y * y) + z * z;
        paug[i] = v;
        const int b = i >> 12;
        atomicAdd(&counts_p[b * NCELL + cell_of(x, y, z)], 1);
    } else {
        const int i = (blockIdx.x - 64) * 256 + threadIdx.x;   // over N1R
        const float x = p1[(size_t)i * 3 + 0];
        const float y = p1[(size_t)i * 3 + 1];
        const float z = p1[(size_t)i * 3 + 2];
        const int b = i >> 14;
        atomicAdd(&counts_q[b * NCELL + cell_of(x, y, z)], 1);
    }
}

// ---------------------------------------------------------------------------
// Exclusive prefix over 512 cells, 4 batches x {points, queries}.
// ---------------------------------------------------------------------------
__global__ __launch_bounds__(512)
void prefix_kernel(const int* __restrict__ counts_p, int* __restrict__ cursors_p,
                   int* __restrict__ starts_p,
                   const int* __restrict__ counts_q, int* __restrict__ cursors_q)
{
    __shared__ int sc[512];
    const int t = threadIdx.x;
    for (int a = 0; a < 8; ++a) {
        const int b = a & 3;
        const int* cnt = (a < 4) ? counts_p + b * NCELL : counts_q + b * NCELL;
        const int v = cnt[t];
        sc[t] = v;
        __syncthreads();
        for (int off = 1; off < 512; off <<= 1) {
            const int add = (t >= off) ? sc[t - off] : 0;
            __syncthreads();
            sc[t] += add;
            __syncthreads();
        }
        const int incl = sc[t];
        const int excl = incl - v;
        if (a < 4) {
            starts_p[b * 513 + t] = excl;
            if (t == 511) starts_p[b * 513 + 512] = incl;   // == 4096
            cursors_p[b * NCELL + t] = excl;
        } else {
            cursors_q[b * NCELL + t] = excl;
        }
        __syncthreads();
    }
}

// ---------------------------------------------------------------------------
// Both scatters in one launch: blocks 0..63 points, 64..319 queries.
// ---------------------------------------------------------------------------
__global__ __launch_bounds__(256)
void scatter_kernel(const float4* __restrict__ paug, const float* __restrict__ p1,
                    int* __restrict__ cursors_p, int* __restrict__ cursors_q,
                    float4* __restrict__ sortedP, unsigned short* __restrict__ sIdx,
                    unsigned short* __restrict__ qlist)
{
    if (blockIdx.x < 64) {
        const int i = blockIdx.x * 256 + threadIdx.x;   // over N2R
        const float4 v = paug[i];
        const int b = i >> 12;
        const int cell = cell_of(v.x, v.y, v.z);
        const int pos = atomicAdd(&cursors_p[b * NCELL + cell], 1);
        sortedP[(size_t)b * NPB + pos] = v;
        sIdx[(size_t)b * NPB + pos] = (unsigned short)(i & 4095);
    } else {
        const int i = (blockIdx.x - 64) * 256 + threadIdx.x;   // over N1R
        const float x = p1[(size_t)i * 3 + 0];
        const float y = p1[(size_t)i * 3 + 1];
        const float z = p1[(size_t)i * 3 + 2];
        const int b = i >> 14;
        const int cell = cell_of(x, y, z);
        const int pos = atomicAdd(&cursors_q[b * NCELL + cell], 1);
        qlist[(size_t)b * NQB + pos] = (unsigned short)(i & 16383);
    }
}

// ---------------------------------------------------------------------------
// Fused tiled GEMM + non-atomic column-stat partials.
// BM x 128 tile, 4 waves; wave quadrant (BM/2) x 64 (MI x 4 MFMA frags).
// LDS ping-pong double buffer: ONE barrier per 32-k chunk (write chunk c+1
// into buf[(c+1)&1] after the barrier, read buf[c&1]).  Reg-staged cvt path
// and MFMA order identical to the proven r2 structure -> Y bitwise same.
// BM=128 for the 65536-row GEMM (512x2 blocks); BM=64 for the 16384-row
// KD=512 GEMM (256x2 blocks = 2 blocks/CU instead of 1).
// Partials: row = blockIdx.x*2 + (wave>>1), disjoint cols per wave -> no
// atomics (r5 lesson: 524K atomics on 512 addrs cost ~30us).
// ---------------------------------------------------------------------------
template<int BM>
__global__ __launch_bounds__(256)
void gemm_fused_kernel(const float* __restrict__ X,
                       const short* __restrict__ WT,
                       const float* __restrict__ bias,
                       float* __restrict__ Y,
                       float* __restrict__ partS, float* __restrict__ partQ,
                       int Kdim)
{
    __shared__ short As[2][BM * ASTRIDE];

    constexpr int MI  = BM / 32;     // m-frags per wave (4 or 2)
    constexpr int NPF = BM / 32;     // v4f prefetch regs per thread (4 or 2)
    constexpr int TPR = 256 / BM;    // threads per row (2 or 4)
    constexpr int FPT = BM / 8;      // floats staged per thread (16 or 8)

    const int bm0 = blockIdx.x * BM;
    const int bn0 = blockIdx.y * 128;
    const int wave = threadIdx.x >> 6;
    const int lane = threadIdx.x & 63;
    const int wm0 = (wave >> 1) * (BM / 2);
    const int wn0 = (wave & 1) * 64;
    const int col = lane & 15, quad = lane >> 4;

    const int srow = threadIdx.x / TPR;
    const int skh  = (threadIdx.x % TPR) * FPT;
    const float* sbase = X + (size_t)(bm0 + srow) * Kdim + skh;
    short* sdst0 = &As[0][srow * ASTRIDE + skh];
    short* sdst1 = &As[1][srow * ASTRIDE + skh];

    v4f acc[MI][4];
#pragma unroll
    for (int i = 0; i < MI; ++i)
#pragma unroll
        for (int j = 0; j < 4; ++j) acc[i][j] = (v4f){0.f, 0.f, 0.f, 0.f};

    const short* wbase = WT + (size_t)(bn0 + wn0 + col) * Kdim + quad * 8;

    // prologue: chunk0 -> regs -> buf0 (no barrier needed); chunk1 -> regs
    v4f pf[NPF];
#pragma unroll
    for (int i = 0; i < NPF; ++i) pf[i] = *(const v4f*)(sbase + i * 4);
    {
        v8s wv;
#pragma unroll
        for (int j = 0; j < NPF / 2; ++j) {
#pragma unroll
            for (int t = 0; t < 4; ++t) {
                wv[t]     = f2bs(pf[2 * j][t]);
                wv[t + 4] = f2bs(pf[2 * j + 1][t]);
            }
            *(v8s*)(sdst0 + j * 8) = wv;
        }
    }
    if (32 < Kdim)
#pragma unroll
        for (int i = 0; i < NPF; ++i) pf[i] = *(const v4f*)(sbase + 32 + i * 4);

    const int NC = Kdim >> 5;
    for (int c = 0; c < NC; ++c) {
        const int k0 = c << 5;
        const bool more = (c + 1 < NC);

        // cvt next chunk (waits on its global loads) before the barrier
        v8s wv[NPF / 2];
        if (more) {
#pragma unroll
            for (int j = 0; j < NPF / 2; ++j)
#pragma unroll
                for (int t = 0; t < 4; ++t) {
                    wv[j][t]     = f2bs(pf[2 * j][t]);
                    wv[j][t + 4] = f2bs(pf[2 * j + 1][t]);
                }
        }
        __syncthreads();   // buf[c&1] writes visible; prior reads of buf[(c+1)&1] done
        if (more) {
            short* sd = (c & 1) ? sdst0 : sdst1;     // buf[(c+1)&1]
#pragma unroll
            for (int j = 0; j < NPF / 2; ++j) *(v8s*)(sd + j * 8) = wv[j];
        }

        // B fragments for this chunk
        v8s bf[4];
#pragma unroll
        for (int ni = 0; ni < 4; ++ni)
            bf[ni] = *(const v8s*)(wbase + (size_t)(ni * 16) * Kdim + k0);

        // global prefetch of chunk c+2 (in flight through MFMA)
        if (c + 2 < NC) {
            const float* np = sbase + k0 + 64;
#pragma unroll
            for (int i = 0; i < NPF; ++i) pf[i] = *(const v4f*)(np + i * 4);
        }

        const short* bufc = As[c & 1];
        v8s a[MI];
#pragma unroll
        for (int mi = 0; mi < MI; ++mi)
            a[mi] = *(const v8s*)(bufc + (wm0 + mi * 16 + col) * ASTRIDE + quad * 8);
#pragma unroll
        for (int mi = 0; mi < MI; ++mi)
#pragma unroll
            for (int ni = 0; ni < 4; ++ni)
                acc[mi][ni] = __builtin_amdgcn_mfma_f32_16x16x32_bf16(a[mi], bf[ni], acc[mi][ni], 0, 0, 0);
    }

    // epilogue: bias + store + non-atomic partial stats
    float* pS = partS + (size_t)(blockIdx.x * 2 + (wave >> 1)) * CC;
    float* pQ = partQ + (size_t)(blockIdx.x * 2 + (wave >> 1)) * CC;
#pragma unroll
    for (int ni = 0; ni < 4; ++ni) {
        const int n = bn0 + wn0 + ni * 16 + col;
        const float bv = bias[n];
        float s = 0.f, q = 0.f;
#pragma unroll
        for (int mi = 0; mi < MI; ++mi) {
            const int m = bm0 + wm0 + mi * 16 + quad * 4;
#pragma unroll
            for (int r = 0; r < 4; ++r) {
                const float y = acc[mi][ni][r] + bv;
                Y[(size_t)(m + r) * CC + n] = y;
                s += y; q += y * y;
            }
        }
        s += __shfl_xor(s, 16); q += __shfl_xor(q, 16);
        s += __shfl_xor(s, 32); q += __shfl_xor(q, 32);
        if (quad == 0) { pS[n] = s; pQ[n] = q; }
    }
}

// ---------------------------------------------------------------------------
// Partial-stat reduce: blocks 0..15 sum BN1's 1024 rows (64 each),
// blocks 16..23 sum BN2's 512 rows (64 each); ~8-16 atomics/address only.
// ---------------------------------------------------------------------------
__global__ __launch_bounds__(256)
void stat_reduce_kernel(const float* __restrict__ pS1, const float* __restrict__ pQ1,
                        const float* __restrict__ pS2, const float* __restrict__ pQ2,
                        float* __restrict__ stats)
{
    const int c = threadIdx.x;
    const bool two = blockIdx.x >= 16;
    const float* pS = two ? pS2 : pS1;
    const float* pQ = two ? pQ2 : pQ1;
    const int r0 = (two ? (blockIdx.x - 16) : blockIdx.x) * 64;
    float s = 0.f, q = 0.f;
    for (int r = r0; r < r0 + 64; ++r) {
        s += pS[(size_t)r * CC + c];
        q += pQ[(size_t)r * CC + c];
    }
    float* st = stats + (two ? 512 : 0);
    atomicAdd(&st[c], s);
    atomicAdd(&st[256 + c], q);
}

// ---------------------------------------------------------------------------
// Finalize BN constants: a = g*rsqrt(var+eps), c = beta - a*mu
// ---------------------------------------------------------------------------
__global__ __launch_bounds__(512)
void finalize_kernel(const float* __restrict__ sums,
                     const float* __restrict__ g1, const float* __restrict__ be1,
                     const float* __restrict__ g2, const float* __restrict__ be2,
                     float* __restrict__ ac)
{
    const int t = threadIdx.x;           // 0..511
    const int c = t & 255;
    const int which = t >> 8;            // 0: BN1, 1: BN2
    const float* s = sums + which * 512;
    const double n = which ? (double)N2R : (double)N1R;
    const double mu = (double)s[c] / n;
    const double var = (double)s[c + 256] / n - mu * mu;
    const float g  = which ? g2[c]  : g1[c];
    const float be = which ? be2[c] : be1[c];
    const double a  = (double)g / sqrt(var + 1e-5);
    const double cv = (double)be - a * mu;
    ac[which * 512 + c]       = (float)a;
    ac[which * 512 + 256 + c] = (float)cv;
}

// ---------------------------------------------------------------------------
// Grid KNN: cell-sorted queries scan their 27-cell neighborhood against the
// batch's cell-sorted points staged in LDS.  Exact fp32 distances
// (bit-matching the reference); lexicographic (d, idx) top-3.  Coverage:
// every point within 0.125 of q lies inside the clamped 27-cell block, so
// b2 < 0.125^2 certifies exactness; else brute-force fallback.
// Block: 256 thr = 128 queries x 2 half-scans (cells 0..13 / 14..26).
// ---------------------------------------------------------------------------
__global__ __launch_bounds__(256)
void knn_grid_kernel(const float* __restrict__ p1,
                     const float4* __restrict__ sortedP,
                     const unsigned short* __restrict__ sIdx16,
                     const int* __restrict__ starts_p,
                     const unsigned short* __restrict__ qlist,
                     int* __restrict__ idx_out, float* __restrict__ w_out,
                     int* __restrict__ failCount, int* __restrict__ failList)
{
#pragma clang fp contract(off)
    __shared__ float4 sP[NPB];                 // 64 KB
    __shared__ unsigned short sI[NPB];         // 8 KB
    __shared__ int sS[513];                    // 2 KB
    __shared__ float mD[128 * 3];              // 1.5 KB
    __shared__ int   mI[128 * 3];              // 1.5 KB

    const int b = blockIdx.x >> 7;             // 128 blocks per batch
    const int slot0 = (blockIdx.x & 127) * 128;
    const int tid = threadIdx.x;
    const int lq = tid & 127;                  // query slot within block
    const int half = tid >> 7;

    // stage the batch's cell-sorted points + idx + starts
    {
        const float4* gp = sortedP + (size_t)b * NPB;
        for (int i = tid; i < NPB; i += 256) sP[i] = gp[i];
        const unsigned int* gi = (const unsigned int*)(sIdx16 + (size_t)b * NPB);
        unsigned int* li = (unsigned int*)sI;
        for (int i = tid; i < NPB / 2; i += 256) li[i] = gi[i];
        const int* gs = starts_p + b * 513;
        for (int i = tid; i < 513; i += 256) sS[i] = gs[i];
    }

    const int q = qlist[(size_t)b * NQB + slot0 + lq];   // batch-local query id
    const int qid = b * NQB + q;
    const float qx = p1[(size_t)qid * 3 + 0];
    const float qy = p1[(size_t)qid * 3 + 1];
    const float qz = p1[(size_t)qid * 3 + 2];
    const float qq = (qx * qx + qy * qy) + qz * qz;
    const int cqx = min(7, (int)(qx * 8.0f));
    const int cqy = min(7, (int)(qy * 8.0f));
    const int cqz = min(7, (int)(qz * 8.0f));

    __syncthreads();

    float b0 = 3.0e38f, b1 = 3.0e38f, b2 = 3.0e38f;
    int i0 = 0x7fffffff, i1 = 0x7fffffff, i2 = 0x7fffffff;

    int n = 0;
    for (int dz = -1; dz <= 1; ++dz)
        for (int dy = -1; dy <= 1; ++dy)
            for (int dx = -1; dx <= 1; ++dx, ++n) {
                if (half ? (n < 14) : (n >= 14)) continue;   // 14 / 13 cell split
                const int cz = cqz + dz, cy = cqy + dy, cx = cqx + dx;
                if (((unsigned)cz | (unsigned)cy | (unsigned)cx) > 7u) continue;
                const int cell = (cz << 6) | (cy << 3) | cx;
                const int ks = sS[cell], ke = sS[cell + 1];
                for (int k = ks; k < ke; ++k) {
                    const float4 P = sP[k];
                    const int si = sI[k];
                    const float dot = fmaf(qz, P.z, fmaf(qy, P.y, qx * P.x));
                    const float d = fmaf(-2.0f, dot, qq + P.w);
                    ins3(d, si, b0, b1, b2, i0, i1, i2);
                }
            }

    if (half) {
        mD[lq * 3 + 0] = b0; mD[lq * 3 + 1] = b1; mD[lq * 3 + 2] = b2;
        mI[lq * 3 + 0] = i0; mI[lq * 3 + 1] = i1; mI[lq * 3 + 2] = i2;
    }
    __syncthreads();
    if (!half) {
#pragma unroll
        for (int r = 0; r < 3; ++r)
            ins3(mD[lq * 3 + r], mI[lq * 3 + r], b0, b1, b2, i0, i1, i2);

        if (!(b2 < GRID_FAIL_R2)) {            // includes <3-found case (b2=3e38)
            const int p = atomicAdd(failCount, 1);
            if (p < N1R) failList[p] = qid;    // capacity-exact; guard is free
        }
        const float r0 = 1.0f / (fmaxf(b0, 0.0f) + 1e-8f);
        const float r1 = 1.0f / (fmaxf(b1, 0.0f) + 1e-8f);
        const float r2 = 1.0f / (fmaxf(b2, 0.0f) + 1e-8f);
        const float rs = (r0 + r1) + r2;
        idx_out[(size_t)qid * 3 + 0] = i0;
        idx_out[(size_t)qid * 3 + 1] = i1;
        idx_out[(size_t)qid * 3 + 2] = i2;
        w_out[(size_t)qid * 3 + 0] = r0 / rs;
        w_out[(size_t)qid * 3 + 1] = r1 / rs;
        w_out[(size_t)qid * 3 + 2] = r2 / rs;
    }
}

// ---------------------------------------------------------------------------
// Brute-force fallback: one wave per failed query, lanes split 4096 points,
// butterfly shuffle-merge of per-lane top-3 triples.  Exact, tiny workload.
// ---------------------------------------------------------------------------
__global__ __launch_bounds__(256)
void knn_bf_kernel(const float* __restrict__ p1,
                   const float4* __restrict__ paug,
                   const int* __restrict__ failCount,
                   const int* __restrict__ failList,
                   int* __restrict__ idx_out, float* __restrict__ w_out)
{
#pragma clang fp contract(off)
    const int nf = min(*failCount, N1R);
    const int gw = (blockIdx.x * 256 + threadIdx.x) >> 6;
    const int lane = threadIdx.x & 63;
    const int nw = (gridDim.x * 256) >> 6;

    for (int fi = gw; fi < nf; fi += nw) {
        const int qid = failList[fi];
        const int b = qid >> 14;
        const float qx = p1[(size_t)qid * 3 + 0];
        const float qy = p1[(size_t)qid * 3 + 1];
        const float qz = p1[(size_t)qid * 3 + 2];
        const float qq = (qx * qx + qy * qy) + qz * qz;

        float b0 = 3.0e38f, b1 = 3.0e38f, b2 = 3.0e38f;
        int i0 = 0x7fffffff, i1 = 0x7fffffff, i2 = 0x7fffffff;

        const float4* pb = paug + (size_t)b * NPB;
        for (int j = lane; j < NPB; j += 64) {
            const float4 P = pb[j];
            const float dot = fmaf(qz, P.z, fmaf(qy, P.y, qx * P.x));
            const float d = fmaf(-2.0f, dot, qq + P.w);
            ins3(d, j, b0, b1, b2, i0, i1, i2);
        }
        // butterfly merge across the wave
        for (int m = 1; m < 64; m <<= 1) {
            const float c0 = __shfl_xor(b0, m), c1 = __shfl_xor(b1, m), c2 = __shfl_xor(b2, m);
            const int j0 = __shfl_xor(i0, m), j1 = __shfl_xor(i1, m), j2 = __shfl_xor(i2, m);
            ins3(c0, j0, b0, b1, b2, i0, i1, i2);
            ins3(c1, j1, b0, b1, b2, i0, i1, i2);
            ins3(c2, j2, b0, b1, b2, i0, i1, i2);
        }
        if (lane == 0) {
            const float r0 = 1.0f / (fmaxf(b0, 0.0f) + 1e-8f);
            const float r1 = 1.0f / (fmaxf(b1, 0.0f) + 1e-8f);
            const float r2 = 1.0f / (fmaxf(b2, 0.0f) + 1e-8f);
            const float rs = (r0 + r1) + r2;
            idx_out[(size_t)qid * 3 + 0] = i0;
            idx_out[(size_t)qid * 3 + 1] = i1;
            idx_out[(size_t)qid * 3 + 2] = i2;
            w_out[(size_t)qid * 3 + 0] = r0 / rs;
            w_out[(size_t)qid * 3 + 1] = r1 / rs;
            w_out[(size_t)qid * 3 + 2] = r2 / rs;
        }
    }
}

// ---------------------------------------------------------------------------
// Final: out[r][c] = relu(a1*Y1+c1) + sum_k w_k * relu(a2*Y2[idx_k]+c2).
// Rows processed in qlist (cell-sorted) order: adjacent blocks handle
// spatially adjacent queries -> their gather rows coincide -> L1/L2 hits.
// All row accesses remain 1KB-contiguous (64 lanes x 16B).
// ---------------------------------------------------------------------------
__global__ __launch_bounds__(256)
void final_kernel(float* __restrict__ Y1out,
                  const float* __restrict__ Y2raw,
                  const float* __restrict__ ac,        // a1,c1,a2,c2 (256 each)
                  const int* __restrict__ idx, const float* __restrict__ w,
                  const unsigned short* __restrict__ qlist)
{
    const int slot = blockIdx.x * 4 + (threadIdx.x >> 6);
    const int b = slot >> 14;
    const int r = b * NQB + qlist[slot];     // cell-sorted row
    const int cg = threadIdx.x & 63;

    v4f a1 = *(const v4f*)(ac + cg * 4);
    v4f c1 = *(const v4f*)(ac + 256 + cg * 4);
    v4f a2 = *(const v4f*)(ac + 512 + cg * 4);
    v4f c2 = *(const v4f*)(ac + 768 + cg * 4);
    v4f y = *(const v4f*)(Y1out + (size_t)r * CC + cg * 4);
    v4f s;
#pragma unroll
    for (int j = 0; j < 4; ++j)
        s[j] = fmaxf(fmaf(a1[j], y[j], c1[j]), 0.f);

    const int*   ir = idx + (size_t)r * 3;
    const float* wr = w   + (size_t)r * 3;
#pragma unroll
    for (int k = 0; k < 3; ++k) {
        const int id = ir[k];
        const float wk = wr[k];
        v4f g = *(const v4f*)(Y2raw + ((size_t)(b * NPB + id)) * CC + cg * 4);
#pragma unroll
        for (int j = 0; j < 4; ++j) {
            const float gv = fmaxf(fmaf(a2[j], g[j], c2[j]), 0.f);   // == bnrelu
            s[j] = fmaf(wk, gv, s[j]);
        }
    }
    *(v4f*)(Y1out + (size_t)r * CC + cg * 4) = s;
}

// ---------------------------------------------------------------------------
extern "C" void kernel_launch(void* const* d_in, const int* in_sizes, int n_in,
                              void* d_out, int out_size, void* d_ws, size_t ws_size,
                              hipStream_t stream)
{
    const float* point1 = (const float*)d_in[0];
    const float* feat1  = (const float*)d_in[1];
    const float* point2 = (const float*)d_in[2];
    const float* feat2  = (const float*)d_in[3];
    const float* W1     = (const float*)d_in[4];
    const float* b1     = (const float*)d_in[5];
    const float* g1     = (const float*)d_in[6];
    const float* beta1  = (const float*)d_in[7];
    const float* W2     = (const float*)d_in[8];
    const float* b2     = (const float*)d_in[9];
    const float* g2     = (const float*)d_in[10];
    const float* beta2  = (const float*)d_in[11];

    float* Y1 = (float*)d_out;                            // 64 MB (reused as output)

    char* ws = (char*)d_ws;
    float*          Y2       = (float*)ws;                                   // 16 MB (raw, BN fused in final)
    float*          stats    = (float*)(ws + (size_t)16777216);              // 4 KB
    int*            counts_p = (int*)  (ws + (size_t)16781312);              // 8 KB
    int*            counts_q = (int*)  (ws + (size_t)16789504);              // 8 KB
    int*            failCnt  = (int*)  (ws + (size_t)16797696);              // 4 KB pad
    int*            cursors_p= (int*)  (ws + (size_t)16801792);              // 8 KB
    int*            cursors_q= (int*)  (ws + (size_t)16809984);              // 8 KB
    int*            starts_p = (int*)  (ws + (size_t)16818176);              // 8.2 KB
    float*          ac       = (float*)(ws + (size_t)16826624);              // 4 KB
    unsigned short* sIdx16   = (unsigned short*)(ws + (size_t)16830720);     // 32 KB
    unsigned short* qlist    = (unsigned short*)(ws + (size_t)16863488);     // 128 KB
    int*            failList = (int*)  (ws + (size_t)16994560);              // 256 KB
    float4*         sortedP  = (float4*)(ws + (size_t)17256704);             // 256 KB
    int*            idxb     = (int*)  (ws + (size_t)17518848);              // 768 KB
    float*          wb       = (float*)(ws + (size_t)18305280);              // 768 KB
    short*          WT1      = (short*)(ws + (size_t)19091712);              // 128 KB
    short*          WT2      = (short*)(ws + (size_t)19222784);              // 256 KB
    float4*         paug     = (float4*)(ws + (size_t)19484928);             // 256 KB
    float*          partS1   = (float*)(ws + (size_t)19747072);              // 1 MB (1024 x 256)
    float*          partQ1   = (float*)(ws + (size_t)20795648);              // 1 MB
    float*          partS2   = (float*)(ws + (size_t)21844224);              // 512 KB (512 x 256)
    float*          partQ2   = (float*)(ws + (size_t)22368512);              // 512 KB

    // zero: stats (4KB) + counts_p (8KB) + counts_q (8KB) + failCnt (4KB)
    hipMemsetAsync(stats, 0, 24576, stream);

    // Prep (merged): W transposes; histograms+paug; prefix; scatters
    wtrans_all_kernel<<<768, 256, 0, stream>>>(W1, W2, WT1, WT2);
    hist_kernel<<<320, 256, 0, stream>>>(point2, point1, paug, counts_p, counts_q);
    prefix_kernel<<<1, 512, 0, stream>>>(counts_p, cursors_p, starts_p, counts_q, cursors_q);
    scatter_kernel<<<320, 256, 0, stream>>>(paug, point1, cursors_p, cursors_q,
                                            sortedP, sIdx16, qlist);

    // Fused GEMM + non-atomic stat partials (1-barrier dbuf K-loop)
    gemm_fused_kernel<128><<<dim3(N1R / 128, 2), 256, 0, stream>>>(feat1, WT1, b1, Y1,
                                                                   partS1, partQ1, 256);
    gemm_fused_kernel<64><<<dim3(N2R / 64, 2), 256, 0, stream>>>(feat2, WT2, b2, Y2,
                                                                 partS2, partQ2, 512);

    // Partial reduce (16 blocks BN1 + 8 blocks BN2) then finalize
    stat_reduce_kernel<<<24, 256, 0, stream>>>(partS1, partQ1, partS2, partQ2, stats);
    finalize_kernel<<<1, 512, 0, stream>>>(stats, g1, beta1, g2, beta2, ac);

    // Grid KNN (exact) + brute-force fallback for boundary failures
    knn_grid_kernel<<<512, 256, 0, stream>>>(point1, sortedP, sIdx16, starts_p,
                                             qlist, idxb, wb, failCnt, failList);
    knn_bf_kernel<<<256, 256, 0, stream>>>(point1, paug, failCnt, failList, idxb, wb);

    // out = relu(bn(Y1)) + weighted gather of relu(bn(Y2)), cell-sorted order
    final_kernel<<<N1R / 4, 256, 0, stream>>>(Y1, Y2, ac, idxb, wb, qlist);
}

// Round 8
// 306.004 us; speedup vs baseline: 1.1938x; 1.0307x over previous
//
#include <hip/hip_runtime.h>
#include <hip/hip_bf16.h>
#include <math.h>

// Problem constants
#define N1R 65536   // B*N1 query rows
#define N2R 16384   // B*N2 point rows
#define NPB 4096    // N2 per batch
#define NQB 16384   // N1 per batch
#define CC  256     // COUT
#define ASTRIDE 40  // LDS A-tile row stride in bf16 elems (80B: 16B-aligned, ~2-way banks)
#define NCELL 512   // 8x8x8 grid cells per batch
#define GRID_FAIL_R2 0.015625f   // (1/8)^2 coverage bound of the 27-cell block

typedef __attribute__((ext_vector_type(4))) float v4f;
typedef __attribute__((ext_vector_type(8))) short v8s;

static __device__ __forceinline__ short f2bs(float f) {
    union { __hip_bfloat16 h; short s; } u;
    u.h = __float2bfloat16(f);
    return u.s;
}

static __device__ __forceinline__ int cell_of(float x, float y, float z) {
    const int cx = min(7, (int)(x * 8.0f));
    const int cy = min(7, (int)(y * 8.0f));
    const int cz = min(7, (int)(z * 8.0f));
    return (cz << 6) | (cy << 3) | cx;
}

// branchless lexicographic (d, idx) top-3 insert; keeps b0<=b1<=b2 sorted
static __device__ __forceinline__ void ins3(float d, int si,
    float& b0, float& b1, float& b2, int& i0, int& i1, int& i2)
{
    const bool lt0 = (d < b0) | ((d == b0) & (si < i0));
    const bool lt1 = (d < b1) | ((d == b1) & (si < i1));
    const bool lt2 = (d < b2) | ((d == b2) & (si < i2));
    b2 = lt1 ? b1 : (lt2 ? d : b2);   i2 = lt1 ? i1 : (lt2 ? si : i2);
    b1 = lt0 ? b0 : (lt1 ? d : b1);   i1 = lt0 ? i0 : (lt1 ? si : i1);
    b0 = lt0 ? d  : b0;               i0 = lt0 ? si : i0;
}

// ---------------------------------------------------------------------------
// Merged prep: W transposes + paug + both cell histograms in ONE launch.
// blocks 0..767  : WT[n][k] = bf16(W[k][n]) for W1 then W2
// blocks 768..831: paug + point histogram (exact fp32, no FMA)
// blocks 832..1087: query histogram
// ---------------------------------------------------------------------------
__global__ __launch_bounds__(256)
void prep_kernel(const float* __restrict__ W1f, const float* __restrict__ W2f,
                 short* __restrict__ WT1, short* __restrict__ WT2,
                 const float* __restrict__ p2, const float* __restrict__ p1,
                 float4* __restrict__ paug,
                 int* __restrict__ counts_p, int* __restrict__ counts_q)
{
#pragma clang fp contract(off)
    const int bid = blockIdx.x;
    if (bid < 768) {
        const int i = bid * 256 + threadIdx.x;   // 0 .. 196607
        if (i < 65536) {
            const int k = i >> 8, n = i & 255;
            WT1[(size_t)n * 256 + k] = f2bs(W1f[i]);
        } else {
            const int j = i - 65536;
            const int k = j >> 8, n = j & 255;
            WT2[(size_t)n * 512 + k] = f2bs(W2f[j]);
        }
    } else if (bid < 832) {
        const int i = (bid - 768) * 256 + threadIdx.x;   // over N2R
        const float x = p2[(size_t)i * 3 + 0];
        const float y = p2[(size_t)i * 3 + 1];
        const float z = p2[(size_t)i * 3 + 2];
        float4 v;
        v.x = x; v.y = y; v.z = z;
        v.w = (x * x + y * y) + z * z;
        paug[i] = v;
        const int b = i >> 12;
        atomicAdd(&counts_p[b * NCELL + cell_of(x, y, z)], 1);
    } else {
        const int i = (bid - 832) * 256 + threadIdx.x;   // over N1R
        const float x = p1[(size_t)i * 3 + 0];
        const float y = p1[(size_t)i * 3 + 1];
        const float z = p1[(size_t)i * 3 + 2];
        const int b = i >> 14;
        atomicAdd(&counts_q[b * NCELL + cell_of(x, y, z)], 1);
    }
}

// ---------------------------------------------------------------------------
// Exclusive prefix over 512 cells, 4 batches x {points, queries}.
// Wave-shuffle Hillis-Steele scan: 3 syncthreads/pass (was 18).
// ---------------------------------------------------------------------------
__global__ __launch_bounds__(512)
void prefix_kernel(const int* __restrict__ counts_p, int* __restrict__ cursors_p,
                   int* __restrict__ starts_p,
                   const int* __restrict__ counts_q, int* __restrict__ cursors_q)
{
    __shared__ int sw[8];      // per-wave totals
    __shared__ int sbase[8];   // per-wave exclusive bases
    const int t = threadIdx.x;
    const int lane = t & 63, wid = t >> 6;
    for (int a = 0; a < 8; ++a) {
        const int b = a & 3;
        const int* cnt = (a < 4) ? counts_p + b * NCELL : counts_q + b * NCELL;
        const int v = cnt[t];
        int incl = v;
#pragma unroll
        for (int off = 1; off < 64; off <<= 1) {
            const int u = __shfl_up(incl, off);
            incl += (lane >= off) ? u : 0;
        }
        if (lane == 63) sw[wid] = incl;
        __syncthreads();
        if (t == 0) {
            int s = 0;
#pragma unroll
            for (int w = 0; w < 8; ++w) { const int x = sw[w]; sbase[w] = s; s += x; }
        }
        __syncthreads();
        const int inclT = incl + sbase[wid];
        const int excl = inclT - v;
        if (a < 4) {
            starts_p[b * 513 + t] = excl;
            if (t == 511) starts_p[b * 513 + 512] = inclT;   // == 4096
            cursors_p[b * NCELL + t] = excl;
        } else {
            cursors_q[b * NCELL + t] = excl;
        }
        __syncthreads();   // sw/sbase reads done before next pass overwrites
    }
}

// ---------------------------------------------------------------------------
// Both scatters in one launch: blocks 0..63 points, 64..319 queries.
// ---------------------------------------------------------------------------
__global__ __launch_bounds__(256)
void scatter_kernel(const float4* __restrict__ paug, const float* __restrict__ p1,
                    int* __restrict__ cursors_p, int* __restrict__ cursors_q,
                    float4* __restrict__ sortedP, unsigned short* __restrict__ sIdx,
                    unsigned short* __restrict__ qlist)
{
    if (blockIdx.x < 64) {
        const int i = blockIdx.x * 256 + threadIdx.x;   // over N2R
        const float4 v = paug[i];
        const int b = i >> 12;
        const int cell = cell_of(v.x, v.y, v.z);
        const int pos = atomicAdd(&cursors_p[b * NCELL + cell], 1);
        sortedP[(size_t)b * NPB + pos] = v;
        sIdx[(size_t)b * NPB + pos] = (unsigned short)(i & 4095);
    } else {
        const int i = (blockIdx.x - 64) * 256 + threadIdx.x;   // over N1R
        const float x = p1[(size_t)i * 3 + 0];
        const float y = p1[(size_t)i * 3 + 1];
        const float z = p1[(size_t)i * 3 + 2];
        const int b = i >> 14;
        const int cell = cell_of(x, y, z);
        const int pos = atomicAdd(&cursors_q[b * NCELL + cell], 1);
        qlist[(size_t)b * NQB + pos] = (unsigned short)(i & 16383);
    }
}

// ---------------------------------------------------------------------------
// GEMM body (device template): BM x 128 tile, 4 waves, 1-barrier ping-pong
// dbuf, reg-staged cvt path; per-thread code identical to the proven r6
// structure -> Y bitwise identical.  Non-atomic stat partials
// (row = bx*2 + wave_m, disjoint cols per y-block/wave; r5 lesson).
// ---------------------------------------------------------------------------
template<int BM>
static __device__ __forceinline__ void gemm_body(
    int bx, int by,
    const float* __restrict__ X, const short* __restrict__ WT,
    const float* __restrict__ bias, float* __restrict__ Y,
    float* __restrict__ partS, float* __restrict__ partQ,
    int Kdim, short* __restrict__ As0, short* __restrict__ As1)
{
    constexpr int MI  = BM / 32;     // m-frags per wave (4 or 2)
    constexpr int NPF = BM / 32;     // v4f prefetch regs per thread (4 or 2)
    constexpr int TPR = 256 / BM;    // threads per row (2 or 4)
    constexpr int FPT = BM / 8;      // floats staged per thread (16 or 8)

    const int bm0 = bx * BM;
    const int bn0 = by * 128;
    const int wave = threadIdx.x >> 6;
    const int lane = threadIdx.x & 63;
    const int wm0 = (wave >> 1) * (BM / 2);
    const int wn0 = (wave & 1) * 64;
    const int col = lane & 15, quad = lane >> 4;

    const int srow = threadIdx.x / TPR;
    const int skh  = (threadIdx.x % TPR) * FPT;
    const float* sbase = X + (size_t)(bm0 + srow) * Kdim + skh;
    short* sdst0 = As0 + srow * ASTRIDE + skh;
    short* sdst1 = As1 + srow * ASTRIDE + skh;

    v4f acc[MI][4];
#pragma unroll
    for (int i = 0; i < MI; ++i)
#pragma unroll
        for (int j = 0; j < 4; ++j) acc[i][j] = (v4f){0.f, 0.f, 0.f, 0.f};

    const short* wbase = WT + (size_t)(bn0 + wn0 + col) * Kdim + quad * 8;

    // prologue: chunk0 -> regs -> buf0; chunk1 -> regs
    v4f pf[NPF];
#pragma unroll
    for (int i = 0; i < NPF; ++i) pf[i] = *(const v4f*)(sbase + i * 4);
    {
        v8s wv;
#pragma unroll
        for (int j = 0; j < NPF / 2; ++j) {
#pragma unroll
            for (int t = 0; t < 4; ++t) {
                wv[t]     = f2bs(pf[2 * j][t]);
                wv[t + 4] = f2bs(pf[2 * j + 1][t]);
            }
            *(v8s*)(sdst0 + j * 8) = wv;
        }
    }
    if (32 < Kdim)
#pragma unroll
        for (int i = 0; i < NPF; ++i) pf[i] = *(const v4f*)(sbase + 32 + i * 4);

    const int NC = Kdim >> 5;
    for (int c = 0; c < NC; ++c) {
        const int k0 = c << 5;
        const bool more = (c + 1 < NC);

        // cvt next chunk (waits on its global loads) before the barrier
        v8s wv[NPF / 2];
        if (more) {
#pragma unroll
            for (int j = 0; j < NPF / 2; ++j)
#pragma unroll
                for (int t = 0; t < 4; ++t) {
                    wv[j][t]     = f2bs(pf[2 * j][t]);
                    wv[j][t + 4] = f2bs(pf[2 * j + 1][t]);
                }
        }
        __syncthreads();   // buf[c&1] writes visible; prior reads of buf[(c+1)&1] done
        if (more) {
            short* sd = (c & 1) ? sdst0 : sdst1;     // buf[(c+1)&1]
#pragma unroll
            for (int j = 0; j < NPF / 2; ++j) *(v8s*)(sd + j * 8) = wv[j];
        }

        // B fragments for this chunk
        v8s bf[4];
#pragma unroll
        for (int ni = 0; ni < 4; ++ni)
            bf[ni] = *(const v8s*)(wbase + (size_t)(ni * 16) * Kdim + k0);

        // global prefetch of chunk c+2 (in flight through MFMA)
        if (c + 2 < NC) {
            const float* np = sbase + k0 + 64;
#pragma unroll
            for (int i = 0; i < NPF; ++i) pf[i] = *(const v4f*)(np + i * 4);
        }

        const short* bufc = (c & 1) ? As1 : As0;
        v8s a[MI];
#pragma unroll
        for (int mi = 0; mi < MI; ++mi)
            a[mi] = *(const v8s*)(bufc + (wm0 + mi * 16 + col) * ASTRIDE + quad * 8);
#pragma unroll
        for (int mi = 0; mi < MI; ++mi)
#pragma unroll
            for (int ni = 0; ni < 4; ++ni)
                acc[mi][ni] = __builtin_amdgcn_mfma_f32_16x16x32_bf16(a[mi], bf[ni], acc[mi][ni], 0, 0, 0);
    }

    // epilogue: bias + store + non-atomic partial stats
    float* pS = partS + (size_t)(bx * 2 + (wave >> 1)) * CC;
    float* pQ = partQ + (size_t)(bx * 2 + (wave >> 1)) * CC;
#pragma unroll
    for (int ni = 0; ni < 4; ++ni) {
        const int n = bn0 + wn0 + ni * 16 + col;
        const float bv = bias[n];
        float s = 0.f, q = 0.f;
#pragma unroll
        for (int mi = 0; mi < MI; ++mi) {
            const int m = bm0 + wm0 + mi * 16 + quad * 4;
#pragma unroll
            for (int r = 0; r < 4; ++r) {
                const float y = acc[mi][ni][r] + bv;
                Y[(size_t)(m + r) * CC + n] = y;
                s += y; q += y * y;
            }
        }
        s += __shfl_xor(s, 16); q += __shfl_xor(q, 16);
        s += __shfl_xor(s, 32); q += __shfl_xor(q, 32);
        if (quad == 0) { pS[n] = s; pQ[n] = q; }
    }
}

// ---------------------------------------------------------------------------
// BOTH GEMMs in one dispatch (concurrent: gemm2's waves fill gemm1's
// latency bubbles; serial-stream launch cost of gemm2 disappears).
// blocks 0..1023: gemm1 (BM=128, KD=256); 1024..1535: gemm2 (BM=64, KD=512).
// ---------------------------------------------------------------------------
__global__ __launch_bounds__(256)
void gemm_both_kernel(const float* __restrict__ feat1, const short* __restrict__ WT1,
                      const float* __restrict__ b1, float* __restrict__ Y1,
                      float* __restrict__ pS1, float* __restrict__ pQ1,
                      const float* __restrict__ feat2, const short* __restrict__ WT2,
                      const float* __restrict__ b2, float* __restrict__ Y2,
                      float* __restrict__ pS2, float* __restrict__ pQ2)
{
    __shared__ short As[2][128 * ASTRIDE];    // 20 KB; BM=64 path uses a prefix
    const int id = blockIdx.x;
    if (id < 1024) {
        gemm_body<128>(id >> 1, id & 1, feat1, WT1, b1, Y1, pS1, pQ1, 256,
                       As[0], As[1]);
    } else {
        const int j = id - 1024;
        gemm_body<64>(j >> 1, j & 1, feat2, WT2, b2, Y2, pS2, pQ2, 512,
                      As[0], As[1]);
    }
}

// ---------------------------------------------------------------------------
// Partial-stat reduce: blocks 0..15 sum BN1's 1024 rows (64 each),
// blocks 16..23 sum BN2's 512 rows (64 each); ~8-16 atomics/address only.
// ---------------------------------------------------------------------------
__global__ __launch_bounds__(256)
void stat_reduce_kernel(const float* __restrict__ pS1, const float* __restrict__ pQ1,
                        const float* __restrict__ pS2, const float* __restrict__ pQ2,
                        float* __restrict__ stats)
{
    const int c = threadIdx.x;
    const bool two = blockIdx.x >= 16;
    const float* pS = two ? pS2 : pS1;
    const float* pQ = two ? pQ2 : pQ1;
    const int r0 = (two ? (blockIdx.x - 16) : blockIdx.x) * 64;
    float s = 0.f, q = 0.f;
    for (int r = r0; r < r0 + 64; ++r) {
        s += pS[(size_t)r * CC + c];
        q += pQ[(size_t)r * CC + c];
    }
    float* st = stats + (two ? 512 : 0);
    atomicAdd(&st[c], s);
    atomicAdd(&st[256 + c], q);
}

// ---------------------------------------------------------------------------
// Finalize BN constants: a = g*rsqrt(var+eps), c = beta - a*mu
// ---------------------------------------------------------------------------
__global__ __launch_bounds__(512)
void finalize_kernel(const float* __restrict__ sums,
                     const float* __restrict__ g1, const float* __restrict__ be1,
                     const float* __restrict__ g2, const float* __restrict__ be2,
                     float* __restrict__ ac)
{
    const int t = threadIdx.x;           // 0..511
    const int c = t & 255;
    const int which = t >> 8;            // 0: BN1, 1: BN2
    const float* s = sums + which * 512;
    const double n = which ? (double)N2R : (double)N1R;
    const double mu = (double)s[c] / n;
    const double var = (double)s[c + 256] / n - mu * mu;
    const float g  = which ? g2[c]  : g1[c];
    const float be = which ? be2[c] : be1[c];
    const double a  = (double)g / sqrt(var + 1e-5);
    const double cv = (double)be - a * mu;
    ac[which * 512 + c]       = (float)a;
    ac[which * 512 + 256 + c] = (float)cv;
}

// ---------------------------------------------------------------------------
// Grid KNN: cell-sorted queries scan their 27-cell neighborhood against the
// batch's cell-sorted points staged in LDS.  Exact fp32 distances
// (bit-matching the reference); lexicographic (d, idx) top-3.  Coverage:
// every point within 0.125 of q lies inside the clamped 27-cell block, so
// b2 < 0.125^2 certifies exactness; else brute-force fallback.
// Block: 256 thr = 128 queries x 2 half-scans (cells 0..13 / 14..26).
// ---------------------------------------------------------------------------
__global__ __launch_bounds__(256)
void knn_grid_kernel(const float* __restrict__ p1,
                     const float4* __restrict__ sortedP,
                     const unsigned short* __restrict__ sIdx16,
                     const int* __restrict__ starts_p,
                     const unsigned short* __restrict__ qlist,
                     int* __restrict__ idx_out, float* __restrict__ w_out,
                     int* __restrict__ failCount, int* __restrict__ failList)
{
#pragma clang fp contract(off)
    __shared__ float4 sP[NPB];                 // 64 KB
    __shared__ unsigned short sI[NPB];         // 8 KB
    __shared__ int sS[513];                    // 2 KB
    __shared__ float mD[128 * 3];              // 1.5 KB
    __shared__ int   mI[128 * 3];              // 1.5 KB

    const int b = blockIdx.x >> 7;             // 128 blocks per batch
    const int slot0 = (blockIdx.x & 127) * 128;
    const int tid = threadIdx.x;
    const int lq = tid & 127;                  // query slot within block
    const int half = tid >> 7;

    // stage the batch's cell-sorted points + idx + starts
    {
        const float4* gp = sortedP + (size_t)b * NPB;
        for (int i = tid; i < NPB; i += 256) sP[i] = gp[i];
        const unsigned int* gi = (const unsigned int*)(sIdx16 + (size_t)b * NPB);
        unsigned int* li = (unsigned int*)sI;
        for (int i = tid; i < NPB / 2; i += 256) li[i] = gi[i];
        const int* gs = starts_p + b * 513;
        for (int i = tid; i < 513; i += 256) sS[i] = gs[i];
    }

    const int q = qlist[(size_t)b * NQB + slot0 + lq];   // batch-local query id
    const int qid = b * NQB + q;
    const float qx = p1[(size_t)qid * 3 + 0];
    const float qy = p1[(size_t)qid * 3 + 1];
    const float qz = p1[(size_t)qid * 3 + 2];
    const float qq = (qx * qx + qy * qy) + qz * qz;
    const int cqx = min(7, (int)(qx * 8.0f));
    const int cqy = min(7, (int)(qy * 8.0f));
    const int cqz = min(7, (int)(qz * 8.0f));

    __syncthreads();

    float b0 = 3.0e38f, b1 = 3.0e38f, b2 = 3.0e38f;
    int i0 = 0x7fffffff, i1 = 0x7fffffff, i2 = 0x7fffffff;

    int n = 0;
    for (int dz = -1; dz <= 1; ++dz)
        for (int dy = -1; dy <= 1; ++dy)
            for (int dx = -1; dx <= 1; ++dx, ++n) {
                if (half ? (n < 14) : (n >= 14)) continue;   // 14 / 13 cell split
                const int cz = cqz + dz, cy = cqy + dy, cx = cqx + dx;
                if (((unsigned)cz | (unsigned)cy | (unsigned)cx) > 7u) continue;
                const int cell = (cz << 6) | (cy << 3) | cx;
                const int ks = sS[cell], ke = sS[cell + 1];
                for (int k = ks; k < ke; ++k) {
                    const float4 P = sP[k];
                    const int si = sI[k];
                    const float dot = fmaf(qz, P.z, fmaf(qy, P.y, qx * P.x));
                    const float d = fmaf(-2.0f, dot, qq + P.w);
                    ins3(d, si, b0, b1, b2, i0, i1, i2);
                }
            }

    if (half) {
        mD[lq * 3 + 0] = b0; mD[lq * 3 + 1] = b1; mD[lq * 3 + 2] = b2;
        mI[lq * 3 + 0] = i0; mI[lq * 3 + 1] = i1; mI[lq * 3 + 2] = i2;
    }
    __syncthreads();
    if (!half) {
#pragma unroll
        for (int r = 0; r < 3; ++r)
            ins3(mD[lq * 3 + r], mI[lq * 3 + r], b0, b1, b2, i0, i1, i2);

        if (!(b2 < GRID_FAIL_R2)) {            // includes <3-found case (b2=3e38)
            const int p = atomicAdd(failCount, 1);
            if (p < N1R) failList[p] = qid;    // capacity-exact; guard is free
        }
        const float r0 = 1.0f / (fmaxf(b0, 0.0f) + 1e-8f);
        const float r1 = 1.0f / (fmaxf(b1, 0.0f) + 1e-8f);
        const float r2 = 1.0f / (fmaxf(b2, 0.0f) + 1e-8f);
        const float rs = (r0 + r1) + r2;
        idx_out[(size_t)qid * 3 + 0] = i0;
        idx_out[(size_t)qid * 3 + 1] = i1;
        idx_out[(size_t)qid * 3 + 2] = i2;
        w_out[(size_t)qid * 3 + 0] = r0 / rs;
        w_out[(size_t)qid * 3 + 1] = r1 / rs;
        w_out[(size_t)qid * 3 + 2] = r2 / rs;
    }
}

// ---------------------------------------------------------------------------
// Brute-force fallback: one wave per failed query, lanes split 4096 points,
// butterfly shuffle-merge of per-lane top-3 triples.  Exact, tiny workload.
// ---------------------------------------------------------------------------
__global__ __launch_bounds__(256)
void knn_bf_kernel(const float* __restrict__ p1,
                   const float4* __restrict__ paug,
                   const int* __restrict__ failCount,
                   const int* __restrict__ failList,
                   int* __restrict__ idx_out, float* __restrict__ w_out)
{
#pragma clang fp contract(off)
    const int nf = min(*failCount, N1R);
    const int gw = (blockIdx.x * 256 + threadIdx.x) >> 6;
    const int lane = threadIdx.x & 63;
    const int nw = (gridDim.x * 256) >> 6;

    for (int fi = gw; fi < nf; fi += nw) {
        const int qid = failList[fi];
        const int b = qid >> 14;
        const float qx = p1[(size_t)qid * 3 + 0];
        const float qy = p1[(size_t)qid * 3 + 1];
        const float qz = p1[(size_t)qid * 3 + 2];
        const float qq = (qx * qx + qy * qy) + qz * qz;

        float b0 = 3.0e38f, b1 = 3.0e38f, b2 = 3.0e38f;
        int i0 = 0x7fffffff, i1 = 0x7fffffff, i2 = 0x7fffffff;

        const float4* pb = paug + (size_t)b * NPB;
        for (int j = lane; j < NPB; j += 64) {
            const float4 P = pb[j];
            const float dot = fmaf(qz, P.z, fmaf(qy, P.y, qx * P.x));
            const float d = fmaf(-2.0f, dot, qq + P.w);
            ins3(d, j, b0, b1, b2, i0, i1, i2);
        }
        // butterfly merge across the wave
        for (int m = 1; m < 64; m <<= 1) {
            const float c0 = __shfl_xor(b0, m), c1 = __shfl_xor(b1, m), c2 = __shfl_xor(b2, m);
            const int j0 = __shfl_xor(i0, m), j1 = __shfl_xor(i1, m), j2 = __shfl_xor(i2, m);
            ins3(c0, j0, b0, b1, b2, i0, i1, i2);
            ins3(c1, j1, b0, b1, b2, i0, i1, i2);
            ins3(c2, j2, b0, b1, b2, i0, i1, i2);
        }
        if (lane == 0) {
            const float r0 = 1.0f / (fmaxf(b0, 0.0f) + 1e-8f);
            const float r1 = 1.0f / (fmaxf(b1, 0.0f) + 1e-8f);
            const float r2 = 1.0f / (fmaxf(b2, 0.0f) + 1e-8f);
            const float rs = (r0 + r1) + r2;
            idx_out[(size_t)qid * 3 + 0] = i0;
            idx_out[(size_t)qid * 3 + 1] = i1;
            idx_out[(size_t)qid * 3 + 2] = i2;
            w_out[(size_t)qid * 3 + 0] = r0 / rs;
            w_out[(size_t)qid * 3 + 1] = r1 / rs;
            w_out[(size_t)qid * 3 + 2] = r2 / rs;
        }
    }
}

// ---------------------------------------------------------------------------
// Final: out[r][c] = relu(a1*Y1+c1) + sum_k w_k * relu(a2*Y2[idx_k]+c2).
// Rows processed in qlist (cell-sorted) order: adjacent blocks handle
// spatially adjacent queries -> their gather rows coincide -> L1/L2 hits.
// ---------------------------------------------------------------------------
__global__ __launch_bounds__(256)
void final_kernel(float* __restrict__ Y1out,
                  const float* __restrict__ Y2raw,
                  const float* __restrict__ ac,        // a1,c1,a2,c2 (256 each)
                  const int* __restrict__ idx, const float* __restrict__ w,
                  const unsigned short* __restrict__ qlist)
{
    const int slot = blockIdx.x * 4 + (threadIdx.x >> 6);
    const int b = slot >> 14;
    const int r = b * NQB + qlist[slot];     // cell-sorted row
    const int cg = threadIdx.x & 63;

    v4f a1 = *(const v4f*)(ac + cg * 4);
    v4f c1 = *(const v4f*)(ac + 256 + cg * 4);
    v4f a2 = *(const v4f*)(ac + 512 + cg * 4);
    v4f c2 = *(const v4f*)(ac + 768 + cg * 4);
    v4f y = *(const v4f*)(Y1out + (size_t)r * CC + cg * 4);
    v4f s;
#pragma unroll
    for (int j = 0; j < 4; ++j)
        s[j] = fmaxf(fmaf(a1[j], y[j], c1[j]), 0.f);

    const int*   ir = idx + (size_t)r * 3;
    const float* wr = w   + (size_t)r * 3;
#pragma unroll
    for (int k = 0; k < 3; ++k) {
        const int id = ir[k];
        const float wk = wr[k];
        v4f g = *(const v4f*)(Y2raw + ((size_t)(b * NPB + id)) * CC + cg * 4);
#pragma unroll
        for (int j = 0; j < 4; ++j) {
            const float gv = fmaxf(fmaf(a2[j], g[j], c2[j]), 0.f);   // == bnrelu
            s[j] = fmaf(wk, gv, s[j]);
        }
    }
    *(v4f*)(Y1out + (size_t)r * CC + cg * 4) = s;
}

// ---------------------------------------------------------------------------
extern "C" void kernel_launch(void* const* d_in, const int* in_sizes, int n_in,
                              void* d_out, int out_size, void* d_ws, size_t ws_size,
                              hipStream_t stream)
{
    const float* point1 = (const float*)d_in[0];
    const float* feat1  = (const float*)d_in[1];
    const float* point2 = (const float*)d_in[2];
    const float* feat2  = (const float*)d_in[3];
    const float* W1     = (const float*)d_in[4];
    const float* b1     = (const float*)d_in[5];
    const float* g1     = (const float*)d_in[6];
    const float* beta1  = (const float*)d_in[7];
    const float* W2     = (const float*)d_in[8];
    const float* b2     = (const float*)d_in[9];
    const float* g2     = (const float*)d_in[10];
    const float* beta2  = (const float*)d_in[11];

    float* Y1 = (float*)d_out;                            // 64 MB (reused as output)

    char* ws = (char*)d_ws;
    float*          Y2       = (float*)ws;                                   // 16 MB (raw, BN fused in final)
    float*          stats    = (float*)(ws + (size_t)16777216);              // 4 KB
    int*            counts_p = (int*)  (ws + (size_t)16781312);              // 8 KB
    int*            counts_q = (int*)  (ws + (size_t)16789504);              // 8 KB
    int*            failCnt  = (int*)  (ws + (size_t)16797696);              // 4 KB pad
    int*            cursors_p= (int*)  (ws + (size_t)16801792);              // 8 KB
    int*            cursors_q= (int*)  (ws + (size_t)16809984);              // 8 KB
    int*            starts_p = (int*)  (ws + (size_t)16818176);              // 8.2 KB
    float*          ac       = (float*)(ws + (size_t)16826624);              // 4 KB
    unsigned short* sIdx16   = (unsigned short*)(ws + (size_t)16830720);     // 32 KB
    unsigned short* qlist    = (unsigned short*)(ws + (size_t)16863488);     // 128 KB
    int*            failList = (int*)  (ws + (size_t)16994560);              // 256 KB
    float4*         sortedP  = (float4*)(ws + (size_t)17256704);             // 256 KB
    int*            idxb     = (int*)  (ws + (size_t)17518848);              // 768 KB
    float*          wb       = (float*)(ws + (size_t)18305280);              // 768 KB
    short*          WT1      = (short*)(ws + (size_t)19091712);              // 128 KB
    short*          WT2      = (short*)(ws + (size_t)19222784);              // 256 KB
    float4*         paug     = (float4*)(ws + (size_t)19484928);             // 256 KB
    float*          partS1   = (float*)(ws + (size_t)19747072);              // 1 MB (1024 x 256)
    float*          partQ1   = (float*)(ws + (size_t)20795648);              // 1 MB
    float*          partS2   = (float*)(ws + (size_t)21844224);              // 512 KB (512 x 256)
    float*          partQ2   = (float*)(ws + (size_t)22368512);              // 512 KB

    // zero: stats (4KB) + counts_p (8KB) + counts_q (8KB) + failCnt (4KB)
    hipMemsetAsync(stats, 0, 24576, stream);

    // Merged prep: W transposes + paug + histograms; prefix; scatters
    prep_kernel<<<1088, 256, 0, stream>>>(W1, W2, WT1, WT2, point2, point1,
                                          paug, counts_p, counts_q);
    prefix_kernel<<<1, 512, 0, stream>>>(counts_p, cursors_p, starts_p, counts_q, cursors_q);
    scatter_kernel<<<320, 256, 0, stream>>>(paug, point1, cursors_p, cursors_q,
                                            sortedP, sIdx16, qlist);

    // Both GEMMs, one dispatch (1024 blocks gemm1 + 512 blocks gemm2)
    gemm_both_kernel<<<1536, 256, 0, stream>>>(feat1, WT1, b1, Y1, partS1, partQ1,
                                               feat2, WT2, b2, Y2, partS2, partQ2);

    // Partial reduce (16 blocks BN1 + 8 blocks BN2) then finalize
    stat_reduce_kernel<<<24, 256, 0, stream>>>(partS1, partQ1, partS2, partQ2, stats);
    finalize_kernel<<<1, 512, 0, stream>>>(stats, g1, beta1, g2, beta2, ac);

    // Grid KNN (exact) + brute-force fallback for boundary failures
    knn_grid_kernel<<<512, 256, 0, stream>>>(point1, sortedP, sIdx16, starts_p,
                                             qlist, idxb, wb, failCnt, failList);
    knn_bf_kernel<<<256, 256, 0, stream>>>(point1, paug, failCnt, failList, idxb, wb);

    // out = relu(bn(Y1)) + weighted gather of relu(bn(Y2)), cell-sorted order
    final_kernel<<<N1R / 4, 256, 0, stream>>>(Y1, Y2, ac, idxb, wb, qlist);
}